// Round 10
// baseline (348.890 us; speedup 1.0000x reference)
//
#include <hip/hip_runtime.h>
#include <cstdint>
#include <cstddef>

#define NF 128          // feature width (IN_F == HID_F == 128)
#define SCAN_B 256

typedef __attribute__((ext_vector_type(4))) float f32x4;
typedef __attribute__((ext_vector_type(8))) short bf16x8;

#define GL2LDS16(g, l) __builtin_amdgcn_global_load_lds(                     \
    (const __attribute__((address_space(1))) unsigned*)(g),                  \
    (__attribute__((address_space(3))) unsigned*)(l), 16, 0, 0)

static __device__ inline float bf2f(short u) {
    union { unsigned u; float f; } v;
    v.u = ((unsigned)(unsigned short)u) << 16;
    return v.f;
}
static __device__ inline short f2bf(float f) {
    union { float f; unsigned u; } v; v.f = f;
    unsigned r = v.u + 0x7FFF + ((v.u >> 16) & 1);  // RNE
    return (short)(r >> 16);
}
static __device__ inline float u2f(unsigned u) {
    union { unsigned u; float f; } v; v.u = u; return v.f;
}
static __device__ inline unsigned f2u(float f) {
    union { float f; unsigned u; } v; v.f = f; return v.u;
}
static __device__ inline unsigned packbf(float lo, float hi) {
    unsigned ul = f2u(lo), uh = f2u(hi);
    ul = ul + 0x7FFF + ((ul >> 16) & 1);
    uh = uh + 0x7FFF + ((uh >> 16) & 1);
    return (ul >> 16) | (uh & 0xFFFF0000u);
}

// ---------------- degree / CSR build ----------------

static __global__ void k_count(const int* __restrict__ dst, int ne, int* __restrict__ counts) {
    int e = blockIdx.x * blockDim.x + threadIdx.x;
    if (e < ne) atomicAdd(&counts[dst[e]], 1);
}

static __global__ void k_scan1(const int* __restrict__ counts, int n,
                               int* __restrict__ row_off, int* __restrict__ bsum) {
    __shared__ int s[SCAN_B];
    int t = threadIdx.x;
    int base = blockIdx.x * SCAN_B;
    int v = (base + t < n) ? counts[base + t] : 0;
    s[t] = v;
    __syncthreads();
    for (int off = 1; off < SCAN_B; off <<= 1) {
        int x = 0;
        if (t >= off) x = s[t - off];
        __syncthreads();
        if (t >= off) s[t] += x;
        __syncthreads();
    }
    if (base + t < n) row_off[base + t] = s[t] - v;
    if (t == SCAN_B - 1) bsum[blockIdx.x] = s[t];
}

static __global__ void k_scan2(int* __restrict__ bsum, int nb) {
    __shared__ int s[512];
    int t = threadIdx.x;
    int v = (t < nb) ? bsum[t] : 0;
    s[t] = v;
    __syncthreads();
    for (int off = 1; off < 512; off <<= 1) {
        int x = 0;
        if (t >= off) x = s[t - off];
        __syncthreads();
        if (t >= off) s[t] += x;
        __syncthreads();
    }
    if (t < nb) bsum[t] = s[t] - v;
}

// scan3 + dinv fused
static __global__ void k_scan3(int* __restrict__ row_off, const int* __restrict__ bsum,
                               int n, int ne, int* __restrict__ cursor,
                               const int* __restrict__ counts, float* __restrict__ dinv) {
    int i = blockIdx.x * SCAN_B + threadIdx.x;
    if (i < n) {
        int v = row_off[i] + bsum[blockIdx.x];
        row_off[i] = v;
        cursor[i] = v;
        float d = fmaxf((float)counts[i], 1.0f);
        dinv[i] = rsqrtf(d);
    }
    if (i == 0) row_off[n] = ne;
}

static __global__ void k_fill(const int* __restrict__ src, const int* __restrict__ dst, int ne,
                              int* __restrict__ cursor, int* __restrict__ csr) {
    int e = blockIdx.x * blockDim.x + threadIdx.x;
    if (e < ne) {
        int d = dst[e];
        int p = atomicAdd(&cursor[d], 1);
        csr[p] = src[e];
    }
}

// ---------------- fp32 -> bf16 convert ----------------

static __global__ __launch_bounds__(256) void k_cvt(const float* __restrict__ x,
                                                    short* __restrict__ y, int n8) {
    int i = blockIdx.x * blockDim.x + threadIdx.x;
    if (i < n8) {
        f32x4 a = *(const f32x4*)&x[(size_t)i * 8];
        f32x4 b = *(const f32x4*)&x[(size_t)i * 8 + 4];
        bf16x8 r;
        r[0] = f2bf(a[0]); r[1] = f2bf(a[1]); r[2] = f2bf(a[2]); r[3] = f2bf(a[3]);
        r[4] = f2bf(b[0]); r[5] = f2bf(b[1]); r[6] = f2bf(b[2]); r[7] = f2bf(b[3]);
        *(bf16x8*)&y[(size_t)i * 8] = r;
    }
}

// merged weight convert: 4 segments [W1:6144][W3:6144][Wm1:2048][Wm2:1024] x8 chunks
static __global__ __launch_bounds__(256) void k_cvtw(
    const float* __restrict__ w1, const float* __restrict__ w3,
    const float* __restrict__ wm1, const float* __restrict__ wm2,
    short* __restrict__ o1, short* __restrict__ o3,
    short* __restrict__ om1, short* __restrict__ om2) {
    int i = blockIdx.x * blockDim.x + threadIdx.x;   // 0..15359
    const float* x; short* y; int off;
    if (i < 6144)       { x = w1;  y = o1;  off = i; }
    else if (i < 12288) { x = w3;  y = o3;  off = i - 6144; }
    else if (i < 14336) { x = wm1; y = om1; off = i - 12288; }
    else                { x = wm2; y = om2; off = i - 14336; }
    f32x4 a = *(const f32x4*)&x[(size_t)off * 8];
    f32x4 b = *(const f32x4*)&x[(size_t)off * 8 + 4];
    bf16x8 r;
    r[0] = f2bf(a[0]); r[1] = f2bf(a[1]); r[2] = f2bf(a[2]); r[3] = f2bf(a[3]);
    r[4] = f2bf(b[0]); r[5] = f2bf(b[1]); r[6] = f2bf(b[2]); r[7] = f2bf(b[3]);
    *(bf16x8*)&y[(size_t)off * 8] = r;
}

// ---------------- Laplacian gather: one wave per node, 8-edge batched loads ----------------

static __global__ __launch_bounds__(256) void k_lap(
    const short* __restrict__ Xin, const short* __restrict__ Xo,
    const int* __restrict__ row_off, const int* __restrict__ csr,
    const float* __restrict__ dinv,
    float a, float b, float c,
    short* __restrict__ out, int n) {
    int node = blockIdx.x * 4 + (threadIdx.x >> 6);
    if (node >= n) return;
    int l = threadIdx.x & 63;
    const unsigned* Xu = (const unsigned*)Xin;
    int e0 = row_off[node], e1 = row_off[node + 1];

    float s0 = 0.f, s1 = 0.f;
    for (int base = e0; base < e1; base += 8) {
        int m = e1 - base;              // edges left (>0)
        int idx = 0;
        if (l < 8 && l < m) idx = csr[base + l];
        unsigned v[8]; float dv[8];
#pragma unroll
        for (int j = 0; j < 8; ++j) {
            int src = __shfl(idx, j, 64);
            bool act = (j < m);
            if (!act) src = 0;
            dv[j] = act ? dinv[src] : 0.f;
            v[j] = Xu[(size_t)src * 64 + l];
        }
#pragma unroll
        for (int j = 0; j < 8; ++j) {
            s0 += u2f(v[j] << 16) * dv[j];
            s1 += u2f(v[j] & 0xFFFF0000u) * dv[j];
        }
    }

    float di = dinv[node];
    unsigned xi = Xu[(size_t)node * 64 + l];
    float y0 = a * (s0 * di) + b * u2f(xi << 16);
    float y1 = a * (s1 * di) + b * u2f(xi & 0xFFFF0000u);
    if (Xo) {
        unsigned xo = ((const unsigned*)Xo)[(size_t)node * 64 + l];
        y0 += c * u2f(xo << 16);
        y1 += c * u2f(xo & 0xFFFF0000u);
    }
    ((unsigned*)out)[(size_t)node * 64 + l] = packbf(y0, y1);
}

// ---------------- conv GEMM: out[M][128] = concat(X0,X1,X2)[M][384] @ Wbf[128][384]^T ----
// BM=128, BN=64, BK=32, 4 waves 2x2 (frag 4x2). 1D grid + bijective XCD swizzle.
// T4 pipeline: 3 LDS buffers, issue 2 K-steps ahead via global_load_lds,
// counted s_waitcnt vmcnt(3) + raw s_barrier per step (never vmcnt(0) mid-loop):
//   iter t: vmcnt(3)[tile t landed] -> barrier -> compute(t%3) -> issue((t+2)%3).
// Race audit: buf (t+2)%3's last reader is compute(t-1); the iter-t barrier
// separates them. Bank conflicts: slot XOR (row>>1)&3 on BOTH source and ds_read.
// mode 2: bn(relu(y+b))   mode 3: relu(y+b)+res.  Output bf16.

static __global__ __launch_bounds__(256) void k_gemm_conv(
    const short* __restrict__ X0, const short* __restrict__ X1, const short* __restrict__ X2,
    const short* __restrict__ Wbf, const float* __restrict__ bias,
    const short* __restrict__ res,
    const float* __restrict__ bng, const float* __restrict__ bnb,
    const float* __restrict__ bnm, const float* __restrict__ bnv,
    int M, int mode, short* __restrict__ out) {
    __shared__ short As[3][128 * 32];
    __shared__ short Bs[3][64 * 32];

    // bijective XCD swizzle (m204); pairs {2k,2k+1} share the A row-block.
    const int nwg = gridDim.x;
    const int q = nwg >> 3, r = nwg & 7;
    const int xcd = blockIdx.x & 7, slot = blockIdx.x >> 3;
    const int flat = (xcd < r ? xcd * (q + 1) : r * (q + 1) + (xcd - r) * q) + slot;
    const int m0 = (flat >> 1) * 128;
    const int n0 = (flat & 1) * 64;

    const int t = threadIdx.x;
    const int wv = t >> 6;
    const int ln = t & 63;
    const int wr = wv >> 1;
    const int wc = wv & 1;
    const int lr = ln & 15;
    const int lk = ln >> 4;

    const short* segs[3] = {X0, X1, X2};

    f32x4 acc[4][2];
#pragma unroll
    for (int i = 0; i < 4; ++i)
#pragma unroll
        for (int j = 0; j < 2; ++j) acc[i][j] = (f32x4){0.f, 0.f, 0.f, 0.f};

    auto issue = [&](int buf, int kt) {
        const short* Xp = segs[kt >> 7];
        const int klocal = kt & 127;
#pragma unroll
        for (int j = 0; j < 2; ++j) {
            int c = (wv * 2 + j) * 64 + ln;
            int row = c >> 2, sl = c & 3;
            int gm = m0 + row;
            if (gm > M - 1) gm = M - 1;            // clamp: valid addr, row unused in epilogue
            const short* g = &Xp[(size_t)gm * 128 + klocal + ((sl ^ ((row >> 1) & 3)) * 8)];
            GL2LDS16(g, &As[buf][(wv * 2 + j) * 512]);   // 64 lanes x 16B = 1KB linear
        }
        {
            int c = wv * 64 + ln;
            int row = c >> 2, sl = c & 3;
            const short* g = &Wbf[(size_t)(n0 + row) * 384 + kt + ((sl ^ ((row >> 1) & 3)) * 8)];
            GL2LDS16(g, &Bs[buf][wv * 512]);
        }
    };
    auto compute = [&](int buf) {
        bf16x8 af[4], bfr[2];
#pragma unroll
        for (int fi = 0; fi < 4; ++fi) {
            int row = wr * 64 + fi * 16 + lr;
            af[fi] = *(const bf16x8*)&As[buf][row * 32 + ((lk ^ ((row >> 1) & 3)) * 8)];
        }
#pragma unroll
        for (int fj = 0; fj < 2; ++fj) {
            int row = wc * 32 + fj * 16 + lr;
            bfr[fj] = *(const bf16x8*)&Bs[buf][row * 32 + ((lk ^ ((row >> 1) & 3)) * 8)];
        }
#pragma unroll
        for (int fi = 0; fi < 4; ++fi)
#pragma unroll
            for (int fj = 0; fj < 2; ++fj)
                acc[fi][fj] = __builtin_amdgcn_mfma_f32_16x16x32_bf16(af[fi], bfr[fj], acc[fi][fj], 0, 0, 0);
    };

    issue(0, 0);        // tile 0 -> buf 0  (3 gload_lds / thread)
    issue(1, 32);       // tile 1 -> buf 1
#pragma unroll
    for (int tgt = 0; tgt < 12; ++tgt) {
        // wait tile tgt's 3 loads (the 3 issued after them stay in flight)
        if (tgt < 11) asm volatile("s_waitcnt vmcnt(3)" ::: "memory");
        else          asm volatile("s_waitcnt vmcnt(0)" ::: "memory");
        __builtin_amdgcn_s_barrier();
        __builtin_amdgcn_sched_barrier(0);
        compute(tgt % 3);
        if (tgt < 10) issue((tgt + 2) % 3, (tgt + 2) * 32);
    }

    // epilogue: C row = lk*4+reg, col = lr
#pragma unroll
    for (int fi = 0; fi < 4; ++fi) {
#pragma unroll
        for (int reg = 0; reg < 4; ++reg) {
            int gm = m0 + wr * 64 + fi * 16 + lk * 4 + reg;
            if (gm >= M) continue;
#pragma unroll
            for (int fj = 0; fj < 2; ++fj) {
                int gn = n0 + wc * 32 + fj * 16 + lr;
                float y = acc[fi][fj][reg] + bias[gn];
                y = fmaxf(y, 0.f);
                if (mode == 2) {
                    float sc = rsqrtf(bnv[gn] + 1e-5f) * bng[gn];
                    y = (y - bnm[gn]) * sc + bnb[gn];
                } else {
                    y += bf2f(res[(size_t)gm * 128 + gn]);
                }
                out[(size_t)gm * 128 + gn] = f2bf(y);
            }
        }
    }
}

// ---------------- fused MLP: out[M][64] = relu(x@Wm1^T+bm1) @ Wm2^T + bm2 ----------------

#define LDP 40

static __global__ __launch_bounds__(256) void k_mlp(
    const short* __restrict__ X, const short* __restrict__ Wm1bf, const float* __restrict__ bm1,
    const short* __restrict__ Wm2bf, const float* __restrict__ bm2,
    int M, float* __restrict__ out) {
    __shared__ short As[64 * LDP];       // phase1 A tile / phase2 B tile
    __shared__ short Bs[128 * LDP];      // phase1 Wm1 tile
    __shared__ short hs[64 * 136];       // h, padded stride 136

    const int t = threadIdx.x;
    const int m0 = blockIdx.x * 64;
    const int w  = t >> 6;
    const int wr = w >> 1;
    const int wc = w & 1;
    const int l  = t & 63;
    const int lr = l & 15;
    const int lk = l >> 4;

    f32x4 acc1[2][4];
#pragma unroll
    for (int i = 0; i < 2; ++i)
#pragma unroll
        for (int j = 0; j < 4; ++j) acc1[i][j] = (f32x4){0.f, 0.f, 0.f, 0.f};

    for (int kt = 0; kt < 128; kt += 32) {
        {
            int row = t >> 2;
            int slot = t & 3;
            int gm = m0 + row;
            bf16x8 v = {0, 0, 0, 0, 0, 0, 0, 0};
            if (gm < M) v = *(const bf16x8*)&X[(size_t)gm * 128 + kt + slot * 8];
            *(bf16x8*)&As[row * LDP + slot * 8] = v;
        }
#pragma unroll
        for (int it = 0; it < 2; ++it) {
            int idx = it * 256 + t;
            int row = idx >> 2;
            int slot = idx & 3;
            bf16x8 v = *(const bf16x8*)&Wm1bf[(size_t)row * 128 + kt + slot * 8];
            *(bf16x8*)&Bs[row * LDP + slot * 8] = v;
        }
        __syncthreads();

        bf16x8 af[2], bfr[4];
#pragma unroll
        for (int fi = 0; fi < 2; ++fi)
            af[fi] = *(const bf16x8*)&As[(wr * 32 + fi * 16 + lr) * LDP + lk * 8];
#pragma unroll
        for (int fj = 0; fj < 4; ++fj)
            bfr[fj] = *(const bf16x8*)&Bs[(wc * 64 + fj * 16 + lr) * LDP + lk * 8];
#pragma unroll
        for (int fi = 0; fi < 2; ++fi)
#pragma unroll
            for (int fj = 0; fj < 4; ++fj)
                acc1[fi][fj] = __builtin_amdgcn_mfma_f32_16x16x32_bf16(af[fi], bfr[fj], acc1[fi][fj], 0, 0, 0);
        __syncthreads();
    }

#pragma unroll
    for (int fi = 0; fi < 2; ++fi) {
#pragma unroll
        for (int reg = 0; reg < 4; ++reg) {
            int rloc = wr * 32 + fi * 16 + lk * 4 + reg;
#pragma unroll
            for (int fj = 0; fj < 4; ++fj) {
                int col = wc * 64 + fj * 16 + lr;
                float y = acc1[fi][fj][reg] + bm1[col];
                hs[rloc * 136 + col] = f2bf(fmaxf(y, 0.f));
            }
        }
    }
    __syncthreads();

    f32x4 acc2[2][2];
#pragma unroll
    for (int i = 0; i < 2; ++i)
#pragma unroll
        for (int j = 0; j < 2; ++j) acc2[i][j] = (f32x4){0.f, 0.f, 0.f, 0.f};

    for (int kt = 0; kt < 128; kt += 32) {
        {
            int row = t >> 2;
            int slot = t & 3;
            bf16x8 v = *(const bf16x8*)&Wm2bf[(size_t)row * 128 + kt + slot * 8];
            *(bf16x8*)&As[row * LDP + slot * 8] = v;
        }
        __syncthreads();

        bf16x8 af[2], bfr[2];
#pragma unroll
        for (int fi = 0; fi < 2; ++fi)
            af[fi] = *(const bf16x8*)&hs[(wr * 32 + fi * 16 + lr) * 136 + kt + lk * 8];
#pragma unroll
        for (int fj = 0; fj < 2; ++fj)
            bfr[fj] = *(const bf16x8*)&As[(wc * 32 + fj * 16 + lr) * LDP + lk * 8];
#pragma unroll
        for (int fi = 0; fi < 2; ++fi)
#pragma unroll
            for (int fj = 0; fj < 2; ++fj)
                acc2[fi][fj] = __builtin_amdgcn_mfma_f32_16x16x32_bf16(af[fi], bfr[fj], acc2[fi][fj], 0, 0, 0);
        __syncthreads();
    }

#pragma unroll
    for (int fi = 0; fi < 2; ++fi) {
#pragma unroll
        for (int reg = 0; reg < 4; ++reg) {
            int gm = m0 + wr * 32 + fi * 16 + lk * 4 + reg;
            if (gm >= M) continue;
#pragma unroll
            for (int fj = 0; fj < 2; ++fj) {
                int gn = wc * 32 + fj * 16 + lr;
                out[(size_t)gm * 64 + gn] = acc2[fi][fj][reg] + bm2[gn];
            }
        }
    }
}

// ---------------- launch ----------------

extern "C" void kernel_launch(void* const* d_in, const int* in_sizes, int n_in,
                              void* d_out, int out_size, void* d_ws, size_t ws_size,
                              hipStream_t stream) {
    const float* features = (const float*)d_in[0];
    const int*   esrc     = (const int*)d_in[1];
    const int*   edst     = (const int*)d_in[2];
    const float* W1   = (const float*)d_in[3];
    const float* b1   = (const float*)d_in[4];
    const float* bng  = (const float*)d_in[5];
    const float* bnb  = (const float*)d_in[6];
    const float* bnm  = (const float*)d_in[7];
    const float* bnv  = (const float*)d_in[8];
    const float* W3   = (const float*)d_in[9];
    const float* b3   = (const float*)d_in[10];
    const float* Wm1  = (const float*)d_in[11];
    const float* bm1  = (const float*)d_in[12];
    const float* Wm2  = (const float*)d_in[13];
    const float* bm2  = (const float*)d_in[14];
    float* out = (float*)d_out;

    const int n  = in_sizes[0] / NF;     // 100000
    const int ne = in_sizes[1];          // 600000

    uint8_t* w = (uint8_t*)d_ws;
    size_t off = 0;
    auto alloc = [&](size_t bytes) -> void* {
        void* p = w + off;
        off = (off + bytes + 255) & ~(size_t)255;
        return p;
    };
    float* dinv   = (float*)alloc((size_t)n * 4);
    int* counts   = (int*)alloc((size_t)n * 4);
    int* row_off  = (int*)alloc(((size_t)n + 1) * 4);
    int* cursor   = (int*)alloc((size_t)n * 4);
    int* csr      = (int*)alloc((size_t)ne * 4);
    int* bsum     = (int*)alloc(4096);
    short* fbf    = (short*)alloc((size_t)n * NF * 2);
    short* bufB   = (short*)alloc((size_t)n * NF * 2);
    short* bufC   = (short*)alloc((size_t)n * NF * 2);
    short* bufD   = (short*)alloc((size_t)n * NF * 2);
    short* bufE   = (short*)alloc((size_t)n * NF * 2);
    short* W1bf   = (short*)alloc((size_t)128 * 384 * 2);
    short* W3bf   = (short*)alloc((size_t)128 * 384 * 2);
    short* Wm1bf  = (short*)alloc((size_t)128 * 128 * 2);
    short* Wm2bf  = (short*)alloc((size_t)64 * 128 * 2);
    (void)ws_size;

    const int TB = 256;
    const int nbE = (ne + TB - 1) / TB;
    const int nbN = (n + TB - 1) / TB;

    hipMemsetAsync(counts, 0, (size_t)n * 4, stream);
    k_count<<<nbE, TB, 0, stream>>>(edst, ne, counts);
    k_scan1<<<nbN, SCAN_B, 0, stream>>>(counts, n, row_off, bsum);
    k_scan2<<<1, 512, 0, stream>>>(bsum, nbN);
    k_scan3<<<nbN, SCAN_B, 0, stream>>>(row_off, bsum, n, ne, cursor, counts, dinv);
    k_fill<<<nbE, TB, 0, stream>>>(esrc, edst, ne, cursor, csr);

    {
        int n8 = n * NF / 8;
        k_cvt<<<(n8 + 255) / 256, 256, 0, stream>>>(features, fbf, n8);
        k_cvtw<<<15360 / 256, 256, 0, stream>>>(W1, W3, Wm1, Wm2, W1bf, W3bf, Wm1bf, Wm2bf);
    }

    const int gm128 = (n + 127) / 128;
    const int gm64  = (n + 63) / 64;
    const int nbL   = (n + 3) / 4;   // lap: 4 nodes per 256-thread block
    const int nwg   = gm128 * 2;     // conv GEMM 1D grid (XCD-swizzled inside)

    // ---- conv1 ----
    k_lap<<<nbL, 256, 0, stream>>>(fbf, nullptr, row_off, csr, dinv, 1.f, -1.f, 0.f, bufB, n);
    k_lap<<<nbL, 256, 0, stream>>>(bufB, fbf, row_off, csr, dinv, 2.f, -2.f, -1.f, bufC, n);
    k_gemm_conv<<<nwg, 256, 0, stream>>>(fbf, bufB, bufC, W1bf, b1,
                                         nullptr, bng, bnb, bnm, bnv, n, 2, bufD);

    // ---- conv2 ----
    k_lap<<<nbL, 256, 0, stream>>>(bufD, nullptr, row_off, csr, dinv, 1.f, -1.f, 0.f, bufB, n);
    k_lap<<<nbL, 256, 0, stream>>>(bufB, bufD, row_off, csr, dinv, 2.f, -2.f, -1.f, bufC, n);
    k_gemm_conv<<<nwg, 256, 0, stream>>>(bufD, bufB, bufC, W3bf, b3,
                                         bufD, nullptr, nullptr, nullptr, nullptr, n, 3, bufE);

    // ---- fused MLP ----
    k_mlp<<<gm64, 256, 0, stream>>>(bufE, Wm1bf, bm1, Wm2bf, bm2, n, out);
}

// Round 11
// 342.701 us; speedup vs baseline: 1.0181x; 1.0181x over previous
//
#include <hip/hip_runtime.h>
#include <cstdint>
#include <cstddef>

#define NF 128          // feature width (IN_F == HID_F == 128)
#define SCAN_B 256

typedef __attribute__((ext_vector_type(4))) float f32x4;
typedef __attribute__((ext_vector_type(8))) short bf16x8;

#define GL2LDS16(g, l) __builtin_amdgcn_global_load_lds(                     \
    (const __attribute__((address_space(1))) unsigned*)(g),                  \
    (__attribute__((address_space(3))) unsigned*)(l), 16, 0, 0)

static __device__ inline float bf2f(short u) {
    union { unsigned u; float f; } v;
    v.u = ((unsigned)(unsigned short)u) << 16;
    return v.f;
}
static __device__ inline short f2bf(float f) {
    union { float f; unsigned u; } v; v.f = f;
    unsigned r = v.u + 0x7FFF + ((v.u >> 16) & 1);  // RNE
    return (short)(r >> 16);
}
static __device__ inline float u2f(unsigned u) {
    union { unsigned u; float f; } v; v.u = u; return v.f;
}
static __device__ inline unsigned f2u(float f) {
    union { float f; unsigned u; } v; v.f = f; return v.u;
}
static __device__ inline unsigned packbf(float lo, float hi) {
    unsigned ul = f2u(lo), uh = f2u(hi);
    ul = ul + 0x7FFF + ((ul >> 16) & 1);
    uh = uh + 0x7FFF + ((uh >> 16) & 1);
    return (ul >> 16) | (uh & 0xFFFF0000u);
}

// ---------------- fused prologue: edge-count + feature cvt + weight cvt ----------------
// block roles: [0, nbE) count | [nbE, nbE+nbF) feature cvt | [nbE+nbF, +60) weight cvt

static __global__ __launch_bounds__(256) void k_pro(
    const int* __restrict__ dst, int ne, int* __restrict__ counts,
    const float* __restrict__ feat, short* __restrict__ fbf, int n8, int nbE, int nbF,
    const float* __restrict__ w1, const float* __restrict__ w3,
    const float* __restrict__ wm1, const float* __restrict__ wm2,
    short* __restrict__ o1, short* __restrict__ o3,
    short* __restrict__ om1, short* __restrict__ om2) {
    int b = blockIdx.x;
    if (b < nbE) {
        int e = b * 256 + threadIdx.x;
        if (e < ne) atomicAdd(&counts[dst[e]], 1);
        return;
    }
    b -= nbE;
    if (b < nbF) {
        int i = b * 256 + threadIdx.x;
        if (i < n8) {
            f32x4 a = *(const f32x4*)&feat[(size_t)i * 8];
            f32x4 c = *(const f32x4*)&feat[(size_t)i * 8 + 4];
            bf16x8 r;
            r[0] = f2bf(a[0]); r[1] = f2bf(a[1]); r[2] = f2bf(a[2]); r[3] = f2bf(a[3]);
            r[4] = f2bf(c[0]); r[5] = f2bf(c[1]); r[6] = f2bf(c[2]); r[7] = f2bf(c[3]);
            *(bf16x8*)&fbf[(size_t)i * 8] = r;
        }
        return;
    }
    b -= nbF;
    int i = b * 256 + threadIdx.x;   // 0..15359
    const float* x; short* y; int off;
    if (i < 6144)       { x = w1;  y = o1;  off = i; }
    else if (i < 12288) { x = w3;  y = o3;  off = i - 6144; }
    else if (i < 14336) { x = wm1; y = om1; off = i - 12288; }
    else                { x = wm2; y = om2; off = i - 14336; }
    f32x4 a = *(const f32x4*)&x[(size_t)off * 8];
    f32x4 c = *(const f32x4*)&x[(size_t)off * 8 + 4];
    bf16x8 r;
    r[0] = f2bf(a[0]); r[1] = f2bf(a[1]); r[2] = f2bf(a[2]); r[3] = f2bf(a[3]);
    r[4] = f2bf(c[0]); r[5] = f2bf(c[1]); r[6] = f2bf(c[2]); r[7] = f2bf(c[3]);
    *(bf16x8*)&y[(size_t)off * 8] = r;
}

// ---------------- scans ----------------

static __global__ void k_scan1(const int* __restrict__ counts, int n,
                               int* __restrict__ row_off, int* __restrict__ bsum) {
    __shared__ int s[SCAN_B];
    int t = threadIdx.x;
    int base = blockIdx.x * SCAN_B;
    int v = (base + t < n) ? counts[base + t] : 0;
    s[t] = v;
    __syncthreads();
    for (int off = 1; off < SCAN_B; off <<= 1) {
        int x = 0;
        if (t >= off) x = s[t - off];
        __syncthreads();
        if (t >= off) s[t] += x;
        __syncthreads();
    }
    if (base + t < n) row_off[base + t] = s[t] - v;
    if (t == SCAN_B - 1) bsum[blockIdx.x] = s[t];
}

static __global__ void k_scan2(int* __restrict__ bsum, int nb) {
    __shared__ int s[512];
    int t = threadIdx.x;
    int v = (t < nb) ? bsum[t] : 0;
    s[t] = v;
    __syncthreads();
    for (int off = 1; off < 512; off <<= 1) {
        int x = 0;
        if (t >= off) x = s[t - off];
        __syncthreads();
        if (t >= off) s[t] += x;
        __syncthreads();
    }
    if (t < nb) bsum[t] = s[t] - v;
}

// scan3 + dinv fused
static __global__ void k_scan3(int* __restrict__ row_off, const int* __restrict__ bsum,
                               int n, int ne, int* __restrict__ cursor,
                               const int* __restrict__ counts, float* __restrict__ dinv) {
    int i = blockIdx.x * SCAN_B + threadIdx.x;
    if (i < n) {
        int v = row_off[i] + bsum[blockIdx.x];
        row_off[i] = v;
        cursor[i] = v;
        float d = fmaxf((float)counts[i], 1.0f);
        dinv[i] = rsqrtf(d);
    }
    if (i == 0) row_off[n] = ne;
}

static __global__ void k_fill(const int* __restrict__ src, const int* __restrict__ dst, int ne,
                              int* __restrict__ cursor, int* __restrict__ csr) {
    int e = blockIdx.x * blockDim.x + threadIdx.x;
    if (e < ne) {
        int d = dst[e];
        int p = atomicAdd(&cursor[d], 1);
        csr[p] = src[e];
    }
}

// ---------------- Laplacian gather: one wave per node ----------------
// Single lane-parallel round for up to 64 edge indices + dinv (lane l owns edge
// e0+l), consumed in shfl-broadcast groups of 8. deg>64 falls back to batch loop.

static __global__ __launch_bounds__(256) void k_lap(
    const short* __restrict__ Xin, const short* __restrict__ Xo,
    const int* __restrict__ row_off, const int* __restrict__ csr,
    const float* __restrict__ dinv,
    float a, float b, float c,
    short* __restrict__ out, int n) {
    int node = blockIdx.x * 4 + (threadIdx.x >> 6);
    if (node >= n) return;
    int l = threadIdx.x & 63;
    const unsigned* Xu = (const unsigned*)Xin;
    int e0 = row_off[node], e1 = row_off[node + 1];
    int deg = e1 - e0;

    // one coalesced round: edge index + its dinv, lane-parallel
    int myi = 0;
    float mydv = 0.f;
    if (l < deg && l < 64) {
        myi = csr[e0 + l];
        mydv = dinv[myi];
    }

    float s0 = 0.f, s1 = 0.f;
    int dcap = deg < 64 ? deg : 64;
    for (int base = 0; base < dcap; base += 8) {
        unsigned v[8]; float dv[8];
#pragma unroll
        for (int j = 0; j < 8; ++j) {
            int src = __shfl(myi, base + j, 64);
            dv[j] = __shfl(mydv, base + j, 64);
            if (base + j >= dcap) { src = 0; dv[j] = 0.f; }
            v[j] = Xu[(size_t)src * 64 + l];
        }
#pragma unroll
        for (int j = 0; j < 8; ++j) {
            s0 += u2f(v[j] << 16) * dv[j];
            s1 += u2f(v[j] & 0xFFFF0000u) * dv[j];
        }
    }
    // rare tail: degree > 64
    for (int base = e0 + 64; base < e1; base += 8) {
        int m = e1 - base;
        int idx = 0;
        if (l < 8 && l < m) idx = csr[base + l];
        unsigned v[8]; float dv[8];
#pragma unroll
        for (int j = 0; j < 8; ++j) {
            int src = __shfl(idx, j, 64);
            bool act = (j < m);
            if (!act) src = 0;
            dv[j] = act ? dinv[src] : 0.f;
            v[j] = Xu[(size_t)src * 64 + l];
        }
#pragma unroll
        for (int j = 0; j < 8; ++j) {
            s0 += u2f(v[j] << 16) * dv[j];
            s1 += u2f(v[j] & 0xFFFF0000u) * dv[j];
        }
    }

    float di = dinv[node];
    unsigned xi = Xu[(size_t)node * 64 + l];
    float y0 = a * (s0 * di) + b * u2f(xi << 16);
    float y1 = a * (s1 * di) + b * u2f(xi & 0xFFFF0000u);
    if (Xo) {
        unsigned xo = ((const unsigned*)Xo)[(size_t)node * 64 + l];
        y0 += c * u2f(xo << 16);
        y1 += c * u2f(xo & 0xFFFF0000u);
    }
    ((unsigned*)out)[(size_t)node * 64 + l] = packbf(y0, y1);
}

// ---------------- conv GEMM (R8 structure, proven 47us) ----------------
// BM=128, BN=64, BK=32, 4 waves 2x2 (frag 4x2). 1D grid + bijective XCD swizzle.
// global_load_lds staging (16B), double-buffered, ONE barrier per K-step.
// Bank conflicts: slot XOR (row>>1)&3 on BOTH source and ds_read (rule #21).
// mode 2: bn(relu(y+b))   mode 3: relu(y+b)+res.  Output bf16.

static __global__ __launch_bounds__(256) void k_gemm_conv(
    const short* __restrict__ X0, const short* __restrict__ X1, const short* __restrict__ X2,
    const short* __restrict__ Wbf, const float* __restrict__ bias,
    const short* __restrict__ res,
    const float* __restrict__ bng, const float* __restrict__ bnb,
    const float* __restrict__ bnm, const float* __restrict__ bnv,
    int M, int mode, short* __restrict__ out) {
    __shared__ short As[2][128 * 32];
    __shared__ short Bs[2][64 * 32];

    // bijective XCD swizzle (m204); pairs {2k,2k+1} share the A row-block.
    const int nwg = gridDim.x;
    const int q = nwg >> 3, r = nwg & 7;
    const int xcd = blockIdx.x & 7, slot = blockIdx.x >> 3;
    const int flat = (xcd < r ? xcd * (q + 1) : r * (q + 1) + (xcd - r) * q) + slot;
    const int m0 = (flat >> 1) * 128;
    const int n0 = (flat & 1) * 64;

    const int t = threadIdx.x;
    const int wv = t >> 6;
    const int ln = t & 63;
    const int wr = wv >> 1;
    const int wc = wv & 1;
    const int lr = ln & 15;
    const int lk = ln >> 4;

    const short* segs[3] = {X0, X1, X2};

    f32x4 acc[4][2];
#pragma unroll
    for (int i = 0; i < 4; ++i)
#pragma unroll
        for (int j = 0; j < 2; ++j) acc[i][j] = (f32x4){0.f, 0.f, 0.f, 0.f};

    auto issue = [&](int buf, int kt) {
        const short* Xp = segs[kt >> 7];
        const int klocal = kt & 127;
#pragma unroll
        for (int j = 0; j < 2; ++j) {
            int c = (wv * 2 + j) * 64 + ln;
            int row = c >> 2, sl = c & 3;
            int gm = m0 + row;
            if (gm > M - 1) gm = M - 1;            // clamp: valid addr, row unused in epilogue
            const short* g = &Xp[(size_t)gm * 128 + klocal + ((sl ^ ((row >> 1) & 3)) * 8)];
            GL2LDS16(g, &As[buf][(wv * 2 + j) * 512]);   // 64 lanes x 16B = 1KB linear
        }
        {
            int c = wv * 64 + ln;
            int row = c >> 2, sl = c & 3;
            const short* g = &Wbf[(size_t)(n0 + row) * 384 + kt + ((sl ^ ((row >> 1) & 3)) * 8)];
            GL2LDS16(g, &Bs[buf][wv * 512]);
        }
    };
    auto compute = [&](int buf) {
        bf16x8 af[4], bfr[2];
#pragma unroll
        for (int fi = 0; fi < 4; ++fi) {
            int row = wr * 64 + fi * 16 + lr;
            af[fi] = *(const bf16x8*)&As[buf][row * 32 + ((lk ^ ((row >> 1) & 3)) * 8)];
        }
#pragma unroll
        for (int fj = 0; fj < 2; ++fj) {
            int row = wc * 32 + fj * 16 + lr;
            bfr[fj] = *(const bf16x8*)&Bs[buf][row * 32 + ((lk ^ ((row >> 1) & 3)) * 8)];
        }
#pragma unroll
        for (int fi = 0; fi < 4; ++fi)
#pragma unroll
            for (int fj = 0; fj < 2; ++fj)
                acc[fi][fj] = __builtin_amdgcn_mfma_f32_16x16x32_bf16(af[fi], bfr[fj], acc[fi][fj], 0, 0, 0);
    };

    issue(0, 0);
    __syncthreads();
#pragma unroll
    for (int tgt = 0; tgt < 12; ++tgt) {
        if (tgt < 11) issue((tgt + 1) & 1, (tgt + 1) * 32);  // async DMA into other buffer
        compute(tgt & 1);                                     // hides the DMA
        __syncthreads();                                      // reads done + loads landed
    }

    // epilogue: C row = lk*4+reg, col = lr
#pragma unroll
    for (int fi = 0; fi < 4; ++fi) {
#pragma unroll
        for (int reg = 0; reg < 4; ++reg) {
            int gm = m0 + wr * 64 + fi * 16 + lk * 4 + reg;
            if (gm >= M) continue;
#pragma unroll
            for (int fj = 0; fj < 2; ++fj) {
                int gn = n0 + wc * 32 + fj * 16 + lr;
                float y = acc[fi][fj][reg] + bias[gn];
                y = fmaxf(y, 0.f);
                if (mode == 2) {
                    float sc = rsqrtf(bnv[gn] + 1e-5f) * bng[gn];
                    y = (y - bnm[gn]) * sc + bnb[gn];
                } else {
                    y += bf2f(res[(size_t)gm * 128 + gn]);
                }
                out[(size_t)gm * 128 + gn] = f2bf(y);
            }
        }
    }
}

// ---------------- fused MLP: out[M][64] = relu(x@Wm1^T+bm1) @ Wm2^T + bm2 ----------------

#define LDP 40

static __global__ __launch_bounds__(256) void k_mlp(
    const short* __restrict__ X, const short* __restrict__ Wm1bf, const float* __restrict__ bm1,
    const short* __restrict__ Wm2bf, const float* __restrict__ bm2,
    int M, float* __restrict__ out) {
    __shared__ short As[64 * LDP];       // phase1 A tile / phase2 B tile
    __shared__ short Bs[128 * LDP];      // phase1 Wm1 tile
    __shared__ short hs[64 * 136];       // h, padded stride 136

    const int t = threadIdx.x;
    const int m0 = blockIdx.x * 64;
    const int w  = t >> 6;
    const int wr = w >> 1;
    const int wc = w & 1;
    const int l  = t & 63;
    const int lr = l & 15;
    const int lk = l >> 4;

    f32x4 acc1[2][4];
#pragma unroll
    for (int i = 0; i < 2; ++i)
#pragma unroll
        for (int j = 0; j < 4; ++j) acc1[i][j] = (f32x4){0.f, 0.f, 0.f, 0.f};

    for (int kt = 0; kt < 128; kt += 32) {
        {
            int row = t >> 2;
            int slot = t & 3;
            int gm = m0 + row;
            bf16x8 v = {0, 0, 0, 0, 0, 0, 0, 0};
            if (gm < M) v = *(const bf16x8*)&X[(size_t)gm * 128 + kt + slot * 8];
            *(bf16x8*)&As[row * LDP + slot * 8] = v;
        }
#pragma unroll
        for (int it = 0; it < 2; ++it) {
            int idx = it * 256 + t;
            int row = idx >> 2;
            int slot = idx & 3;
            bf16x8 v = *(const bf16x8*)&Wm1bf[(size_t)row * 128 + kt + slot * 8];
            *(bf16x8*)&Bs[row * LDP + slot * 8] = v;
        }
        __syncthreads();

        bf16x8 af[2], bfr[4];
#pragma unroll
        for (int fi = 0; fi < 2; ++fi)
            af[fi] = *(const bf16x8*)&As[(wr * 32 + fi * 16 + lr) * LDP + lk * 8];
#pragma unroll
        for (int fj = 0; fj < 4; ++fj)
            bfr[fj] = *(const bf16x8*)&Bs[(wc * 64 + fj * 16 + lr) * LDP + lk * 8];
#pragma unroll
        for (int fi = 0; fi < 2; ++fi)
#pragma unroll
            for (int fj = 0; fj < 4; ++fj)
                acc1[fi][fj] = __builtin_amdgcn_mfma_f32_16x16x32_bf16(af[fi], bfr[fj], acc1[fi][fj], 0, 0, 0);
        __syncthreads();
    }

#pragma unroll
    for (int fi = 0; fi < 2; ++fi) {
#pragma unroll
        for (int reg = 0; reg < 4; ++reg) {
            int rloc = wr * 32 + fi * 16 + lk * 4 + reg;
#pragma unroll
            for (int fj = 0; fj < 4; ++fj) {
                int col = wc * 64 + fj * 16 + lr;
                float y = acc1[fi][fj][reg] + bm1[col];
                hs[rloc * 136 + col] = f2bf(fmaxf(y, 0.f));
            }
        }
    }
    __syncthreads();

    f32x4 acc2[2][2];
#pragma unroll
    for (int i = 0; i < 2; ++i)
#pragma unroll
        for (int j = 0; j < 2; ++j) acc2[i][j] = (f32x4){0.f, 0.f, 0.f, 0.f};

    for (int kt = 0; kt < 128; kt += 32) {
        {
            int row = t >> 2;
            int slot = t & 3;
            bf16x8 v = *(const bf16x8*)&Wm2bf[(size_t)row * 128 + kt + slot * 8];
            *(bf16x8*)&As[row * LDP + slot * 8] = v;
        }
        __syncthreads();

        bf16x8 af[2], bfr[2];
#pragma unroll
        for (int fi = 0; fi < 2; ++fi)
            af[fi] = *(const bf16x8*)&hs[(wr * 32 + fi * 16 + lr) * 136 + kt + lk * 8];
#pragma unroll
        for (int fj = 0; fj < 2; ++fj)
            bfr[fj] = *(const bf16x8*)&As[(wc * 32 + fj * 16 + lr) * LDP + lk * 8];
#pragma unroll
        for (int fi = 0; fi < 2; ++fi)
#pragma unroll
            for (int fj = 0; fj < 2; ++fj)
                acc2[fi][fj] = __builtin_amdgcn_mfma_f32_16x16x32_bf16(af[fi], bfr[fj], acc2[fi][fj], 0, 0, 0);
        __syncthreads();
    }

#pragma unroll
    for (int fi = 0; fi < 2; ++fi) {
#pragma unroll
        for (int reg = 0; reg < 4; ++reg) {
            int gm = m0 + wr * 32 + fi * 16 + lk * 4 + reg;
            if (gm >= M) continue;
#pragma unroll
            for (int fj = 0; fj < 2; ++fj) {
                int gn = wc * 32 + fj * 16 + lr;
                out[(size_t)gm * 64 + gn] = acc2[fi][fj][reg] + bm2[gn];
            }
        }
    }
}

// ---------------- launch ----------------

extern "C" void kernel_launch(void* const* d_in, const int* in_sizes, int n_in,
                              void* d_out, int out_size, void* d_ws, size_t ws_size,
                              hipStream_t stream) {
    const float* features = (const float*)d_in[0];
    const int*   esrc     = (const int*)d_in[1];
    const int*   edst     = (const int*)d_in[2];
    const float* W1   = (const float*)d_in[3];
    const float* b1   = (const float*)d_in[4];
    const float* bng  = (const float*)d_in[5];
    const float* bnb  = (const float*)d_in[6];
    const float* bnm  = (const float*)d_in[7];
    const float* bnv  = (const float*)d_in[8];
    const float* W3   = (const float*)d_in[9];
    const float* b3   = (const float*)d_in[10];
    const float* Wm1  = (const float*)d_in[11];
    const float* bm1  = (const float*)d_in[12];
    const float* Wm2  = (const float*)d_in[13];
    const float* bm2  = (const float*)d_in[14];
    float* out = (float*)d_out;

    const int n  = in_sizes[0] / NF;     // 100000
    const int ne = in_sizes[1];          // 600000

    uint8_t* w = (uint8_t*)d_ws;
    size_t off = 0;
    auto alloc = [&](size_t bytes) -> void* {
        void* p = w + off;
        off = (off + bytes + 255) & ~(size_t)255;
        return p;
    };
    float* dinv   = (float*)alloc((size_t)n * 4);
    int* counts   = (int*)alloc((size_t)n * 4);
    int* row_off  = (int*)alloc(((size_t)n + 1) * 4);
    int* cursor   = (int*)alloc((size_t)n * 4);
    int* csr      = (int*)alloc((size_t)ne * 4);
    int* bsum     = (int*)alloc(4096);
    short* fbf    = (short*)alloc((size_t)n * NF * 2);
    short* bufB   = (short*)alloc((size_t)n * NF * 2);
    short* bufC   = (short*)alloc((size_t)n * NF * 2);
    short* bufD   = (short*)alloc((size_t)n * NF * 2);
    short* bufE   = (short*)alloc((size_t)n * NF * 2);
    short* W1bf   = (short*)alloc((size_t)128 * 384 * 2);
    short* W3bf   = (short*)alloc((size_t)128 * 384 * 2);
    short* Wm1bf  = (short*)alloc((size_t)128 * 128 * 2);
    short* Wm2bf  = (short*)alloc((size_t)64 * 128 * 2);
    (void)ws_size;

    const int TB = 256;
    const int nbE = (ne + TB - 1) / TB;
    const int nbN = (n + TB - 1) / TB;
    const int n8  = n * NF / 8;
    const int nbF = (n8 + TB - 1) / TB;

    hipMemsetAsync(counts, 0, (size_t)n * 4, stream);
    k_pro<<<nbE + nbF + 60, TB, 0, stream>>>(edst, ne, counts,
                                             features, fbf, n8, nbE, nbF,
                                             W1, W3, Wm1, Wm2, W1bf, W3bf, Wm1bf, Wm2bf);
    k_scan1<<<nbN, SCAN_B, 0, stream>>>(counts, n, row_off, bsum);
    k_scan2<<<1, 512, 0, stream>>>(bsum, nbN);
    k_scan3<<<nbN, SCAN_B, 0, stream>>>(row_off, bsum, n, ne, cursor, counts, dinv);
    k_fill<<<nbE, TB, 0, stream>>>(esrc, edst, ne, cursor, csr);

    const int gm128 = (n + 127) / 128;
    const int gm64  = (n + 63) / 64;
    const int nbL   = (n + 3) / 4;   // lap: 4 nodes per 256-thread block
    const int nwg   = gm128 * 2;     // conv GEMM 1D grid (XCD-swizzled inside)

    // ---- conv1 ----
    k_lap<<<nbL, 256, 0, stream>>>(fbf, nullptr, row_off, csr, dinv, 1.f, -1.f, 0.f, bufB, n);
    k_lap<<<nbL, 256, 0, stream>>>(bufB, fbf, row_off, csr, dinv, 2.f, -2.f, -1.f, bufC, n);
    k_gemm_conv<<<nwg, 256, 0, stream>>>(fbf, bufB, bufC, W1bf, b1,
                                         nullptr, bng, bnb, bnm, bnv, n, 2, bufD);

    // ---- conv2 ----
    k_lap<<<nbL, 256, 0, stream>>>(bufD, nullptr, row_off, csr, dinv, 1.f, -1.f, 0.f, bufB, n);
    k_lap<<<nbL, 256, 0, stream>>>(bufB, bufD, row_off, csr, dinv, 2.f, -2.f, -1.f, bufC, n);
    k_gemm_conv<<<nwg, 256, 0, stream>>>(bufD, bufB, bufC, W3bf, b3,
                                         bufD, nullptr, nullptr, nullptr, nullptr, n, 3, bufE);

    // ---- fused MLP ----
    k_mlp<<<gm64, 256, 0, stream>>>(bufE, Wm1bf, bm1, Wm2bf, bm2, n, out);
}

// Round 12
// 341.324 us; speedup vs baseline: 1.0222x; 1.0040x over previous
//
#include <hip/hip_runtime.h>
#include <cstdint>
#include <cstddef>

#define NF 128          // feature width (IN_F == HID_F == 128)
#define SCAN_B 256

typedef __attribute__((ext_vector_type(4))) float f32x4;
typedef __attribute__((ext_vector_type(8))) short bf16x8;

#define GL2LDS16(g, l) __builtin_amdgcn_global_load_lds(                     \
    (const __attribute__((address_space(1))) unsigned*)(g),                  \
    (__attribute__((address_space(3))) unsigned*)(l), 16, 0, 0)

static __device__ inline float bf2f(short u) {
    union { unsigned u; float f; } v;
    v.u = ((unsigned)(unsigned short)u) << 16;
    return v.f;
}
static __device__ inline short f2bf(float f) {
    union { float f; unsigned u; } v; v.f = f;
    unsigned r = v.u + 0x7FFF + ((v.u >> 16) & 1);  // RNE
    return (short)(r >> 16);
}
static __device__ inline float u2f(unsigned u) {
    union { unsigned u; float f; } v; v.u = u; return v.f;
}
static __device__ inline unsigned f2u(float f) {
    union { float f; unsigned u; } v; v.f = f; return v.u;
}
static __device__ inline unsigned packbf(float lo, float hi) {
    unsigned ul = f2u(lo), uh = f2u(hi);
    ul = ul + 0x7FFF + ((ul >> 16) & 1);
    uh = uh + 0x7FFF + ((uh >> 16) & 1);
    return (ul >> 16) | (uh & 0xFFFF0000u);
}

// ---------------- fused prologue: edge-count + feature cvt + weight cvt ----------------
// block roles: [0, nbE) count | [nbE, nbE+nbF) feature cvt | [nbE+nbF, +60) weight cvt

static __global__ __launch_bounds__(256) void k_pro(
    const int* __restrict__ dst, int ne, int* __restrict__ counts,
    const float* __restrict__ feat, short* __restrict__ fbf, int n8, int nbE, int nbF,
    const float* __restrict__ w1, const float* __restrict__ w3,
    const float* __restrict__ wm1, const float* __restrict__ wm2,
    short* __restrict__ o1, short* __restrict__ o3,
    short* __restrict__ om1, short* __restrict__ om2) {
    int b = blockIdx.x;
    if (b < nbE) {
        int e = b * 256 + threadIdx.x;
        if (e < ne) atomicAdd(&counts[dst[e]], 1);
        return;
    }
    b -= nbE;
    if (b < nbF) {
        int i = b * 256 + threadIdx.x;
        if (i < n8) {
            f32x4 a = *(const f32x4*)&feat[(size_t)i * 8];
            f32x4 c = *(const f32x4*)&feat[(size_t)i * 8 + 4];
            bf16x8 r;
            r[0] = f2bf(a[0]); r[1] = f2bf(a[1]); r[2] = f2bf(a[2]); r[3] = f2bf(a[3]);
            r[4] = f2bf(c[0]); r[5] = f2bf(c[1]); r[6] = f2bf(c[2]); r[7] = f2bf(c[3]);
            *(bf16x8*)&fbf[(size_t)i * 8] = r;
        }
        return;
    }
    b -= nbF;
    int i = b * 256 + threadIdx.x;   // 0..15359
    const float* x; short* y; int off;
    if (i < 6144)       { x = w1;  y = o1;  off = i; }
    else if (i < 12288) { x = w3;  y = o3;  off = i - 6144; }
    else if (i < 14336) { x = wm1; y = om1; off = i - 12288; }
    else                { x = wm2; y = om2; off = i - 14336; }
    f32x4 a = *(const f32x4*)&x[(size_t)off * 8];
    f32x4 c = *(const f32x4*)&x[(size_t)off * 8 + 4];
    bf16x8 r;
    r[0] = f2bf(a[0]); r[1] = f2bf(a[1]); r[2] = f2bf(a[2]); r[3] = f2bf(a[3]);
    r[4] = f2bf(c[0]); r[5] = f2bf(c[1]); r[6] = f2bf(c[2]); r[7] = f2bf(c[3]);
    *(bf16x8*)&y[(size_t)off * 8] = r;
}

// ---------------- scans ----------------

static __global__ void k_scan1(const int* __restrict__ counts, int n,
                               int* __restrict__ row_off, int* __restrict__ bsum) {
    __shared__ int s[SCAN_B];
    int t = threadIdx.x;
    int base = blockIdx.x * SCAN_B;
    int v = (base + t < n) ? counts[base + t] : 0;
    s[t] = v;
    __syncthreads();
    for (int off = 1; off < SCAN_B; off <<= 1) {
        int x = 0;
        if (t >= off) x = s[t - off];
        __syncthreads();
        if (t >= off) s[t] += x;
        __syncthreads();
    }
    if (base + t < n) row_off[base + t] = s[t] - v;
    if (t == SCAN_B - 1) bsum[blockIdx.x] = s[t];
}

static __global__ void k_scan2(int* __restrict__ bsum, int nb) {
    __shared__ int s[512];
    int t = threadIdx.x;
    int v = (t < nb) ? bsum[t] : 0;
    s[t] = v;
    __syncthreads();
    for (int off = 1; off < 512; off <<= 1) {
        int x = 0;
        if (t >= off) x = s[t - off];
        __syncthreads();
        if (t >= off) s[t] += x;
        __syncthreads();
    }
    if (t < nb) bsum[t] = s[t] - v;
}

// scan3 + dinv fused
static __global__ void k_scan3(int* __restrict__ row_off, const int* __restrict__ bsum,
                               int n, int ne, int* __restrict__ cursor,
                               const int* __restrict__ counts, float* __restrict__ dinv) {
    int i = blockIdx.x * SCAN_B + threadIdx.x;
    if (i < n) {
        int v = row_off[i] + bsum[blockIdx.x];
        row_off[i] = v;
        cursor[i] = v;
        float d = fmaxf((float)counts[i], 1.0f);
        dinv[i] = rsqrtf(d);
    }
    if (i == 0) row_off[n] = ne;
}

static __global__ void k_fill(const int* __restrict__ src, const int* __restrict__ dst, int ne,
                              int* __restrict__ cursor, int* __restrict__ csr) {
    int e = blockIdx.x * blockDim.x + threadIdx.x;
    if (e < ne) {
        int d = dst[e];
        int p = atomicAdd(&cursor[d], 1);
        csr[p] = src[e];
    }
}

// ---------------- Laplacian gather: one wave per node ----------------
// Single lane-parallel round for up to 64 edge indices + dinv (lane l owns edge
// e0+l), consumed in shfl-broadcast groups of 8. deg>64 falls back to batch loop.

static __global__ __launch_bounds__(256) void k_lap(
    const short* __restrict__ Xin, const short* __restrict__ Xo,
    const int* __restrict__ row_off, const int* __restrict__ csr,
    const float* __restrict__ dinv,
    float a, float b, float c,
    short* __restrict__ out, int n) {
    int node = blockIdx.x * 4 + (threadIdx.x >> 6);
    if (node >= n) return;
    int l = threadIdx.x & 63;
    const unsigned* Xu = (const unsigned*)Xin;
    int e0 = row_off[node], e1 = row_off[node + 1];
    int deg = e1 - e0;

    // one coalesced round: edge index + its dinv, lane-parallel
    int myi = 0;
    float mydv = 0.f;
    if (l < deg && l < 64) {
        myi = csr[e0 + l];
        mydv = dinv[myi];
    }

    float s0 = 0.f, s1 = 0.f;
    int dcap = deg < 64 ? deg : 64;
    for (int base = 0; base < dcap; base += 8) {
        unsigned v[8]; float dv[8];
#pragma unroll
        for (int j = 0; j < 8; ++j) {
            int src = __shfl(myi, base + j, 64);
            dv[j] = __shfl(mydv, base + j, 64);
            if (base + j >= dcap) { src = 0; dv[j] = 0.f; }
            v[j] = Xu[(size_t)src * 64 + l];
        }
#pragma unroll
        for (int j = 0; j < 8; ++j) {
            s0 += u2f(v[j] << 16) * dv[j];
            s1 += u2f(v[j] & 0xFFFF0000u) * dv[j];
        }
    }
    // rare tail: degree > 64
    for (int base = e0 + 64; base < e1; base += 8) {
        int m = e1 - base;
        int idx = 0;
        if (l < 8 && l < m) idx = csr[base + l];
        unsigned v[8]; float dv[8];
#pragma unroll
        for (int j = 0; j < 8; ++j) {
            int src = __shfl(idx, j, 64);
            bool act = (j < m);
            if (!act) src = 0;
            dv[j] = act ? dinv[src] : 0.f;
            v[j] = Xu[(size_t)src * 64 + l];
        }
#pragma unroll
        for (int j = 0; j < 8; ++j) {
            s0 += u2f(v[j] << 16) * dv[j];
            s1 += u2f(v[j] & 0xFFFF0000u) * dv[j];
        }
    }

    float di = dinv[node];
    unsigned xi = Xu[(size_t)node * 64 + l];
    float y0 = a * (s0 * di) + b * u2f(xi << 16);
    float y1 = a * (s1 * di) + b * u2f(xi & 0xFFFF0000u);
    if (Xo) {
        unsigned xo = ((const unsigned*)Xo)[(size_t)node * 64 + l];
        y0 += c * u2f(xo << 16);
        y1 += c * u2f(xo & 0xFFFF0000u);
    }
    ((unsigned*)out)[(size_t)node * 64 + l] = packbf(y0, y1);
}

// ---------------- conv GEMM: out[M][128] = concat(X0,X1,X2)[M][384] @ Wbf[128][384]^T ----
// BM=128, BN=128 (A read ONCE -> halved per-CU port traffic vs BN=64), BK=32.
// 512 threads = 8 waves (2 row x 4 col), wave tile 64x32, frag 4x2.
// 782 blocks @ 8 waves: ALL co-resident (256CU x 4-block wave limit) -> no tail.
// gload_lds 16B staging, double-buffered, ONE barrier per K-step (R8 machinery).
// Bank conflicts: slot XOR (row>>1)&3 on BOTH source and ds_read (rule #21).
// mode 2: bn(relu(y+b))   mode 3: relu(y+b)+res.  Output bf16.

static __global__ __launch_bounds__(512) void k_gemm_conv(
    const short* __restrict__ X0, const short* __restrict__ X1, const short* __restrict__ X2,
    const short* __restrict__ Wbf, const float* __restrict__ bias,
    const short* __restrict__ res,
    const float* __restrict__ bng, const float* __restrict__ bnb,
    const float* __restrict__ bnm, const float* __restrict__ bnv,
    int M, int mode, short* __restrict__ out) {
    __shared__ short As[2][128 * 32];
    __shared__ short Bs[2][128 * 32];

    // bijective XCD swizzle (m204)
    const int nwg = gridDim.x;
    const int q = nwg >> 3, r = nwg & 7;
    const int xcd = blockIdx.x & 7, slot = blockIdx.x >> 3;
    const int flat = (xcd < r ? xcd * (q + 1) : r * (q + 1) + (xcd - r) * q) + slot;
    const int m0 = flat * 128;

    const int t = threadIdx.x;
    const int wv = t >> 6;          // 0..7
    const int ln = t & 63;
    const int wr = wv >> 2;         // 0..1 (M)
    const int wc = wv & 3;          // 0..3 (N)
    const int lr = ln & 15;
    const int lk = ln >> 4;

    const short* segs[3] = {X0, X1, X2};

    f32x4 acc[4][2];
#pragma unroll
    for (int i = 0; i < 4; ++i)
#pragma unroll
        for (int j = 0; j < 2; ++j) acc[i][j] = (f32x4){0.f, 0.f, 0.f, 0.f};

    // staging: 16 instruction-groups of 1KB (64 lanes x 16B). groups 0-7 -> As, 8-15 -> Bs.
    // chunk c = g*64+ln; A: row=c>>2, sl=c&3. B: cb=c-512, row=cb>>2, sl=cb&3.
    auto issue = [&](int buf, int kt) {
        const short* Xp = segs[kt >> 7];
        const int klocal = kt & 127;
#pragma unroll
        for (int j = 0; j < 2; ++j) {
            int g = wv * 2 + j;            // 0..15
            int c = g * 64 + ln;
            if (g < 8) {
                int row = c >> 2, sl = c & 3;
                int gm = m0 + row;
                if (gm > M - 1) gm = M - 1;   // clamp: valid addr, row unused in epilogue
                const short* src = &Xp[(size_t)gm * 128 + klocal + ((sl ^ ((row >> 1) & 3)) * 8)];
                GL2LDS16(src, &As[buf][g * 512]);
            } else {
                int cb = c - 512;
                int row = cb >> 2, sl = cb & 3;
                const short* src = &Wbf[(size_t)row * 384 + kt + ((sl ^ ((row >> 1) & 3)) * 8)];
                GL2LDS16(src, &Bs[buf][(g - 8) * 512]);
            }
        }
    };
    auto compute = [&](int buf) {
        bf16x8 af[4], bfr[2];
#pragma unroll
        for (int fi = 0; fi < 4; ++fi) {
            int row = wr * 64 + fi * 16 + lr;
            af[fi] = *(const bf16x8*)&As[buf][row * 32 + ((lk ^ ((row >> 1) & 3)) * 8)];
        }
#pragma unroll
        for (int fj = 0; fj < 2; ++fj) {
            int row = wc * 32 + fj * 16 + lr;
            bfr[fj] = *(const bf16x8*)&Bs[buf][row * 32 + ((lk ^ ((row >> 1) & 3)) * 8)];
        }
#pragma unroll
        for (int fi = 0; fi < 4; ++fi)
#pragma unroll
            for (int fj = 0; fj < 2; ++fj)
                acc[fi][fj] = __builtin_amdgcn_mfma_f32_16x16x32_bf16(af[fi], bfr[fj], acc[fi][fj], 0, 0, 0);
    };

    issue(0, 0);
    __syncthreads();
#pragma unroll
    for (int tgt = 0; tgt < 12; ++tgt) {
        if (tgt < 11) issue((tgt + 1) & 1, (tgt + 1) * 32);  // async DMA into other buffer
        compute(tgt & 1);                                     // hides the DMA
        __syncthreads();                                      // reads done + loads landed
    }

    // epilogue: C row = lk*4+reg, col = lr
#pragma unroll
    for (int fi = 0; fi < 4; ++fi) {
#pragma unroll
        for (int reg = 0; reg < 4; ++reg) {
            int gm = m0 + wr * 64 + fi * 16 + lk * 4 + reg;
            if (gm >= M) continue;
#pragma unroll
            for (int fj = 0; fj < 2; ++fj) {
                int gn = wc * 32 + fj * 16 + lr;
                float y = acc[fi][fj][reg] + bias[gn];
                y = fmaxf(y, 0.f);
                if (mode == 2) {
                    float sc = rsqrtf(bnv[gn] + 1e-5f) * bng[gn];
                    y = (y - bnm[gn]) * sc + bnb[gn];
                } else {
                    y += bf2f(res[(size_t)gm * 128 + gn]);
                }
                out[(size_t)gm * 128 + gn] = f2bf(y);
            }
        }
    }
}

// ---------------- fused MLP: out[M][64] = relu(x@Wm1^T+bm1) @ Wm2^T + bm2 ----------------

#define LDP 40

static __global__ __launch_bounds__(256) void k_mlp(
    const short* __restrict__ X, const short* __restrict__ Wm1bf, const float* __restrict__ bm1,
    const short* __restrict__ Wm2bf, const float* __restrict__ bm2,
    int M, float* __restrict__ out) {
    __shared__ short As[64 * LDP];       // phase1 A tile / phase2 B tile
    __shared__ short Bs[128 * LDP];      // phase1 Wm1 tile
    __shared__ short hs[64 * 136];       // h, padded stride 136

    const int t = threadIdx.x;
    const int m0 = blockIdx.x * 64;
    const int w  = t >> 6;
    const int wr = w >> 1;
    const int wc = w & 1;
    const int l  = t & 63;
    const int lr = l & 15;
    const int lk = l >> 4;

    f32x4 acc1[2][4];
#pragma unroll
    for (int i = 0; i < 2; ++i)
#pragma unroll
        for (int j = 0; j < 4; ++j) acc1[i][j] = (f32x4){0.f, 0.f, 0.f, 0.f};

    for (int kt = 0; kt < 128; kt += 32) {
        {
            int row = t >> 2;
            int slot = t & 3;
            int gm = m0 + row;
            bf16x8 v = {0, 0, 0, 0, 0, 0, 0, 0};
            if (gm < M) v = *(const bf16x8*)&X[(size_t)gm * 128 + kt + slot * 8];
            *(bf16x8*)&As[row * LDP + slot * 8] = v;
        }
#pragma unroll
        for (int it = 0; it < 2; ++it) {
            int idx = it * 256 + t;
            int row = idx >> 2;
            int slot = idx & 3;
            bf16x8 v = *(const bf16x8*)&Wm1bf[(size_t)row * 128 + kt + slot * 8];
            *(bf16x8*)&Bs[row * LDP + slot * 8] = v;
        }
        __syncthreads();

        bf16x8 af[2], bfr[4];
#pragma unroll
        for (int fi = 0; fi < 2; ++fi)
            af[fi] = *(const bf16x8*)&As[(wr * 32 + fi * 16 + lr) * LDP + lk * 8];
#pragma unroll
        for (int fj = 0; fj < 4; ++fj)
            bfr[fj] = *(const bf16x8*)&Bs[(wc * 64 + fj * 16 + lr) * LDP + lk * 8];
#pragma unroll
        for (int fi = 0; fi < 2; ++fi)
#pragma unroll
            for (int fj = 0; fj < 4; ++fj)
                acc1[fi][fj] = __builtin_amdgcn_mfma_f32_16x16x32_bf16(af[fi], bfr[fj], acc1[fi][fj], 0, 0, 0);
        __syncthreads();
    }

#pragma unroll
    for (int fi = 0; fi < 2; ++fi) {
#pragma unroll
        for (int reg = 0; reg < 4; ++reg) {
            int rloc = wr * 32 + fi * 16 + lk * 4 + reg;
#pragma unroll
            for (int fj = 0; fj < 4; ++fj) {
                int col = wc * 64 + fj * 16 + lr;
                float y = acc1[fi][fj][reg] + bm1[col];
                hs[rloc * 136 + col] = f2bf(fmaxf(y, 0.f));
            }
        }
    }
    __syncthreads();

    f32x4 acc2[2][2];
#pragma unroll
    for (int i = 0; i < 2; ++i)
#pragma unroll
        for (int j = 0; j < 2; ++j) acc2[i][j] = (f32x4){0.f, 0.f, 0.f, 0.f};

    for (int kt = 0; kt < 128; kt += 32) {
        {
            int row = t >> 2;
            int slot = t & 3;
            bf16x8 v = *(const bf16x8*)&Wm2bf[(size_t)row * 128 + kt + slot * 8];
            *(bf16x8*)&As[row * LDP + slot * 8] = v;
        }
        __syncthreads();

        bf16x8 af[2], bfr[2];
#pragma unroll
        for (int fi = 0; fi < 2; ++fi)
            af[fi] = *(const bf16x8*)&hs[(wr * 32 + fi * 16 + lr) * 136 + kt + lk * 8];
#pragma unroll
        for (int fj = 0; fj < 2; ++fj)
            bfr[fj] = *(const bf16x8*)&As[(wc * 32 + fj * 16 + lr) * LDP + lk * 8];
#pragma unroll
        for (int fi = 0; fi < 2; ++fi)
#pragma unroll
            for (int fj = 0; fj < 2; ++fj)
                acc2[fi][fj] = __builtin_amdgcn_mfma_f32_16x16x32_bf16(af[fi], bfr[fj], acc2[fi][fj], 0, 0, 0);
        __syncthreads();
    }

#pragma unroll
    for (int fi = 0; fi < 2; ++fi) {
#pragma unroll
        for (int reg = 0; reg < 4; ++reg) {
            int gm = m0 + wr * 32 + fi * 16 + lk * 4 + reg;
            if (gm >= M) continue;
#pragma unroll
            for (int fj = 0; fj < 2; ++fj) {
                int gn = wc * 32 + fj * 16 + lr;
                out[(size_t)gm * 64 + gn] = acc2[fi][fj][reg] + bm2[gn];
            }
        }
    }
}

// ---------------- launch ----------------

extern "C" void kernel_launch(void* const* d_in, const int* in_sizes, int n_in,
                              void* d_out, int out_size, void* d_ws, size_t ws_size,
                              hipStream_t stream) {
    const float* features = (const float*)d_in[0];
    const int*   esrc     = (const int*)d_in[1];
    const int*   edst     = (const int*)d_in[2];
    const float* W1   = (const float*)d_in[3];
    const float* b1   = (const float*)d_in[4];
    const float* bng  = (const float*)d_in[5];
    const float* bnb  = (const float*)d_in[6];
    const float* bnm  = (const float*)d_in[7];
    const float* bnv  = (const float*)d_in[8];
    const float* W3   = (const float*)d_in[9];
    const float* b3   = (const float*)d_in[10];
    const float* Wm1  = (const float*)d_in[11];
    const float* bm1  = (const float*)d_in[12];
    const float* Wm2  = (const float*)d_in[13];
    const float* bm2  = (const float*)d_in[14];
    float* out = (float*)d_out;

    const int n  = in_sizes[0] / NF;     // 100000
    const int ne = in_sizes[1];          // 600000

    uint8_t* w = (uint8_t*)d_ws;
    size_t off = 0;
    auto alloc = [&](size_t bytes) -> void* {
        void* p = w + off;
        off = (off + bytes + 255) & ~(size_t)255;
        return p;
    };
    float* dinv   = (float*)alloc((size_t)n * 4);
    int* counts   = (int*)alloc((size_t)n * 4);
    int* row_off  = (int*)alloc(((size_t)n + 1) * 4);
    int* cursor   = (int*)alloc((size_t)n * 4);
    int* csr      = (int*)alloc((size_t)ne * 4);
    int* bsum     = (int*)alloc(4096);
    short* fbf    = (short*)alloc((size_t)n * NF * 2);
    short* bufB   = (short*)alloc((size_t)n * NF * 2);
    short* bufC   = (short*)alloc((size_t)n * NF * 2);
    short* bufD   = (short*)alloc((size_t)n * NF * 2);
    short* bufE   = (short*)alloc((size_t)n * NF * 2);
    short* W1bf   = (short*)alloc((size_t)128 * 384 * 2);
    short* W3bf   = (short*)alloc((size_t)128 * 384 * 2);
    short* Wm1bf  = (short*)alloc((size_t)128 * 128 * 2);
    short* Wm2bf  = (short*)alloc((size_t)64 * 128 * 2);
    (void)ws_size;

    const int TB = 256;
    const int nbE = (ne + TB - 1) / TB;
    const int nbN = (n + TB - 1) / TB;
    const int n8  = n * NF / 8;
    const int nbF = (n8 + TB - 1) / TB;

    hipMemsetAsync(counts, 0, (size_t)n * 4, stream);
    k_pro<<<nbE + nbF + 60, TB, 0, stream>>>(edst, ne, counts,
                                             features, fbf, n8, nbE, nbF,
                                             W1, W3, Wm1, Wm2, W1bf, W3bf, Wm1bf, Wm2bf);
    k_scan1<<<nbN, SCAN_B, 0, stream>>>(counts, n, row_off, bsum);
    k_scan2<<<1, 512, 0, stream>>>(bsum, nbN);
    k_scan3<<<nbN, SCAN_B, 0, stream>>>(row_off, bsum, n, ne, cursor, counts, dinv);
    k_fill<<<nbE, TB, 0, stream>>>(esrc, edst, ne, cursor, csr);

    const int gm128 = (n + 127) / 128;
    const int gm64  = (n + 63) / 64;
    const int nbL   = (n + 3) / 4;   // lap: 4 nodes per 256-thread block

    // ---- conv1 ----
    k_lap<<<nbL, 256, 0, stream>>>(fbf, nullptr, row_off, csr, dinv, 1.f, -1.f, 0.f, bufB, n);
    k_lap<<<nbL, 256, 0, stream>>>(bufB, fbf, row_off, csr, dinv, 2.f, -2.f, -1.f, bufC, n);
    k_gemm_conv<<<gm128, 512, 0, stream>>>(fbf, bufB, bufC, W1bf, b1,
                                           nullptr, bng, bnb, bnm, bnv, n, 2, bufD);

    // ---- conv2 ----
    k_lap<<<nbL, 256, 0, stream>>>(bufD, nullptr, row_off, csr, dinv, 1.f, -1.f, 0.f, bufB, n);
    k_lap<<<nbL, 256, 0, stream>>>(bufB, bufD, row_off, csr, dinv, 2.f, -2.f, -1.f, bufC, n);
    k_gemm_conv<<<gm128, 512, 0, stream>>>(bufD, bufB, bufC, W3bf, b3,
                                           bufD, nullptr, nullptr, nullptr, nullptr, n, 3, bufE);

    // ---- fused MLP ----
    k_mlp<<<gm64, 256, 0, stream>>>(bufE, Wm1bf, bm1, Wm2bf, bm2, n, out);
}

// Round 13
// 332.330 us; speedup vs baseline: 1.0498x; 1.0271x over previous
//
#include <hip/hip_runtime.h>
#include <cstdint>
#include <cstddef>

#define NF 128          // feature width (IN_F == HID_F == 128)
#define SCAN_B 256

typedef __attribute__((ext_vector_type(4))) float f32x4;
typedef __attribute__((ext_vector_type(8))) short bf16x8;

#define GL2LDS16(g, l) __builtin_amdgcn_global_load_lds(                     \
    (const __attribute__((address_space(1))) unsigned*)(g),                  \
    (__attribute__((address_space(3))) unsigned*)(l), 16, 0, 0)

static __device__ inline float bf2f(short u) {
    union { unsigned u; float f; } v;
    v.u = ((unsigned)(unsigned short)u) << 16;
    return v.f;
}
static __device__ inline short f2bf(float f) {
    union { float f; unsigned u; } v; v.f = f;
    unsigned r = v.u + 0x7FFF + ((v.u >> 16) & 1);  // RNE
    return (short)(r >> 16);
}
static __device__ inline float u2f(unsigned u) {
    union { unsigned u; float f; } v; v.u = u; return v.f;
}
static __device__ inline unsigned f2u(float f) {
    union { float f; unsigned u; } v; v.f = f; return v.u;
}
static __device__ inline unsigned packbf(float lo, float hi) {
    unsigned ul = f2u(lo), uh = f2u(hi);
    ul = ul + 0x7FFF + ((ul >> 16) & 1);
    uh = uh + 0x7FFF + ((uh >> 16) & 1);
    return (ul >> 16) | (uh & 0xFFFF0000u);
}

// ---------------- fused prologue: edge-count + feature cvt + weight cvt ----------------
// block roles: [0, nbE) count | [nbE, nbE+nbF) feature cvt | [nbE+nbF, +60) weight cvt

static __global__ __launch_bounds__(256) void k_pro(
    const int* __restrict__ dst, int ne, int* __restrict__ counts,
    const float* __restrict__ feat, short* __restrict__ fbf, int n8, int nbE, int nbF,
    const float* __restrict__ w1, const float* __restrict__ w3,
    const float* __restrict__ wm1, const float* __restrict__ wm2,
    short* __restrict__ o1, short* __restrict__ o3,
    short* __restrict__ om1, short* __restrict__ om2) {
    int b = blockIdx.x;
    if (b < nbE) {
        int e = b * 256 + threadIdx.x;
        if (e < ne) atomicAdd(&counts[dst[e]], 1);
        return;
    }
    b -= nbE;
    if (b < nbF) {
        int i = b * 256 + threadIdx.x;
        if (i < n8) {
            f32x4 a = *(const f32x4*)&feat[(size_t)i * 8];
            f32x4 c = *(const f32x4*)&feat[(size_t)i * 8 + 4];
            bf16x8 r;
            r[0] = f2bf(a[0]); r[1] = f2bf(a[1]); r[2] = f2bf(a[2]); r[3] = f2bf(a[3]);
            r[4] = f2bf(c[0]); r[5] = f2bf(c[1]); r[6] = f2bf(c[2]); r[7] = f2bf(c[3]);
            *(bf16x8*)&fbf[(size_t)i * 8] = r;
        }
        return;
    }
    b -= nbF;
    int i = b * 256 + threadIdx.x;   // 0..15359
    const float* x; short* y; int off;
    if (i < 6144)       { x = w1;  y = o1;  off = i; }
    else if (i < 12288) { x = w3;  y = o3;  off = i - 6144; }
    else if (i < 14336) { x = wm1; y = om1; off = i - 12288; }
    else                { x = wm2; y = om2; off = i - 14336; }
    f32x4 a = *(const f32x4*)&x[(size_t)off * 8];
    f32x4 c = *(const f32x4*)&x[(size_t)off * 8 + 4];
    bf16x8 r;
    r[0] = f2bf(a[0]); r[1] = f2bf(a[1]); r[2] = f2bf(a[2]); r[3] = f2bf(a[3]);
    r[4] = f2bf(c[0]); r[5] = f2bf(c[1]); r[6] = f2bf(c[2]); r[7] = f2bf(c[3]);
    *(bf16x8*)&y[(size_t)off * 8] = r;
}

// ---------------- scans ----------------

static __global__ void k_scan1(const int* __restrict__ counts, int n,
                               int* __restrict__ row_off, int* __restrict__ bsum) {
    __shared__ int s[SCAN_B];
    int t = threadIdx.x;
    int base = blockIdx.x * SCAN_B;
    int v = (base + t < n) ? counts[base + t] : 0;
    s[t] = v;
    __syncthreads();
    for (int off = 1; off < SCAN_B; off <<= 1) {
        int x = 0;
        if (t >= off) x = s[t - off];
        __syncthreads();
        if (t >= off) s[t] += x;
        __syncthreads();
    }
    if (base + t < n) row_off[base + t] = s[t] - v;
    if (t == SCAN_B - 1) bsum[blockIdx.x] = s[t];
}

static __global__ void k_scan2(int* __restrict__ bsum, int nb) {
    __shared__ int s[512];
    int t = threadIdx.x;
    int v = (t < nb) ? bsum[t] : 0;
    s[t] = v;
    __syncthreads();
    for (int off = 1; off < 512; off <<= 1) {
        int x = 0;
        if (t >= off) x = s[t - off];
        __syncthreads();
        if (t >= off) s[t] += x;
        __syncthreads();
    }
    if (t < nb) bsum[t] = s[t] - v;
}

// scan3 + dinv fused
static __global__ void k_scan3(int* __restrict__ row_off, const int* __restrict__ bsum,
                               int n, int ne, int* __restrict__ cursor,
                               const int* __restrict__ counts, float* __restrict__ dinv) {
    int i = blockIdx.x * SCAN_B + threadIdx.x;
    if (i < n) {
        int v = row_off[i] + bsum[blockIdx.x];
        row_off[i] = v;
        cursor[i] = v;
        float d = fmaxf((float)counts[i], 1.0f);
        dinv[i] = rsqrtf(d);
    }
    if (i == 0) row_off[n] = ne;
}

static __global__ void k_fill(const int* __restrict__ src, const int* __restrict__ dst, int ne,
                              int* __restrict__ cursor, int* __restrict__ csr) {
    int e = blockIdx.x * blockDim.x + threadIdx.x;
    if (e < ne) {
        int d = dst[e];
        int p = atomicAdd(&cursor[d], 1);
        csr[p] = src[e];
    }
}

// ---------------- Laplacian gather: one wave per node, readlane broadcast ----------------
// Lane l owns edge e0+l (index + dinv in one coalesced round). Consumption uses
// __builtin_amdgcn_readlane (wave-uniform lane id): edge index + weight land in
// SGPRs -> scalar-base addressing + SGPR multiplier, no ds_bpermute.

static __global__ __launch_bounds__(256) void k_lap(
    const short* __restrict__ Xin, const short* __restrict__ Xo,
    const int* __restrict__ row_off, const int* __restrict__ csr,
    const float* __restrict__ dinv,
    float a, float b, float c,
    short* __restrict__ out, int n) {
    int node = blockIdx.x * 4 + (threadIdx.x >> 6);
    if (node >= n) return;
    int l = threadIdx.x & 63;
    const unsigned* Xu = (const unsigned*)Xin;
    int e0 = row_off[node], e1 = row_off[node + 1];
    int deg = e1 - e0;

    // one coalesced round: edge index + its dinv, lane-parallel
    int myi = 0;
    float mydv = 0.f;
    if (l < deg && l < 64) {
        myi = csr[e0 + l];
        mydv = dinv[myi];
    }

    float s0 = 0.f, s1 = 0.f;
    int dcap = deg < 64 ? deg : 64;
    for (int base = 0; base < dcap; base += 8) {
        unsigned v[8]; float dv[8];
#pragma unroll
        for (int j = 0; j < 8; ++j) {
            int jj = base + j;
            bool act = (jj < dcap);                       // wave-uniform
            int lane = act ? jj : base;                   // masked -> edge base's row (L1-hot)
            int src = __builtin_amdgcn_readlane(myi, lane);        // SGPR
            unsigned dvb = __builtin_amdgcn_readlane((int)f2u(mydv), lane);
            dv[j] = act ? u2f(dvb) : 0.f;
            v[j] = Xu[(size_t)src * 64 + l];              // scalar base + lane*4
        }
#pragma unroll
        for (int j = 0; j < 8; ++j) {
            s0 += u2f(v[j] << 16) * dv[j];
            s1 += u2f(v[j] & 0xFFFF0000u) * dv[j];
        }
    }
    // rare tail: degree > 64
    for (int base = e0 + 64; base < e1; base += 8) {
        int m = e1 - base;
        int idx = 0;
        if (l < 8 && l < m) idx = csr[base + l];
        unsigned v[8]; float dv[8];
#pragma unroll
        for (int j = 0; j < 8; ++j) {
            int src = __shfl(idx, j, 64);
            bool act = (j < m);
            if (!act) src = 0;
            dv[j] = act ? dinv[src] : 0.f;
            v[j] = Xu[(size_t)src * 64 + l];
        }
#pragma unroll
        for (int j = 0; j < 8; ++j) {
            s0 += u2f(v[j] << 16) * dv[j];
            s1 += u2f(v[j] & 0xFFFF0000u) * dv[j];
        }
    }

    float di = dinv[node];
    unsigned xi = Xu[(size_t)node * 64 + l];
    float y0 = a * (s0 * di) + b * u2f(xi << 16);
    float y1 = a * (s1 * di) + b * u2f(xi & 0xFFFF0000u);
    if (Xo) {
        unsigned xo = ((const unsigned*)Xo)[(size_t)node * 64 + l];
        y0 += c * u2f(xo << 16);
        y1 += c * u2f(xo & 0xFFFF0000u);
    }
    ((unsigned*)out)[(size_t)node * 64 + l] = packbf(y0, y1);
}

// ---------------- conv GEMM (R11 structure, ~46us floor) ----------------
// BM=128, BN=128, BK=32, 512 threads = 8 waves (2x4), wave tile 64x32, frag 4x2.
// gload_lds 16B staging, double-buffered, ONE barrier per K-step.
// Bank conflicts: slot XOR (row>>1)&3 on BOTH source and ds_read (rule #21).
// mode 2: bn(relu(y+b))   mode 3: relu(y+b)+res.  Output bf16.

static __global__ __launch_bounds__(512) void k_gemm_conv(
    const short* __restrict__ X0, const short* __restrict__ X1, const short* __restrict__ X2,
    const short* __restrict__ Wbf, const float* __restrict__ bias,
    const short* __restrict__ res,
    const float* __restrict__ bng, const float* __restrict__ bnb,
    const float* __restrict__ bnm, const float* __restrict__ bnv,
    int M, int mode, short* __restrict__ out) {
    __shared__ short As[2][128 * 32];
    __shared__ short Bs[2][128 * 32];

    // bijective XCD swizzle (m204)
    const int nwg = gridDim.x;
    const int q = nwg >> 3, r = nwg & 7;
    const int xcd = blockIdx.x & 7, slot = blockIdx.x >> 3;
    const int flat = (xcd < r ? xcd * (q + 1) : r * (q + 1) + (xcd - r) * q) + slot;
    const int m0 = flat * 128;

    const int t = threadIdx.x;
    const int wv = t >> 6;          // 0..7
    const int ln = t & 63;
    const int wr = wv >> 2;         // 0..1 (M)
    const int wc = wv & 3;          // 0..3 (N)
    const int lr = ln & 15;
    const int lk = ln >> 4;

    const short* segs[3] = {X0, X1, X2};

    f32x4 acc[4][2];
#pragma unroll
    for (int i = 0; i < 4; ++i)
#pragma unroll
        for (int j = 0; j < 2; ++j) acc[i][j] = (f32x4){0.f, 0.f, 0.f, 0.f};

    auto issue = [&](int buf, int kt) {
        const short* Xp = segs[kt >> 7];
        const int klocal = kt & 127;
#pragma unroll
        for (int j = 0; j < 2; ++j) {
            int g = wv * 2 + j;            // 0..15
            int c = g * 64 + ln;
            if (g < 8) {
                int row = c >> 2, sl = c & 3;
                int gm = m0 + row;
                if (gm > M - 1) gm = M - 1;   // clamp: valid addr, row unused in epilogue
                const short* src = &Xp[(size_t)gm * 128 + klocal + ((sl ^ ((row >> 1) & 3)) * 8)];
                GL2LDS16(src, &As[buf][g * 512]);
            } else {
                int cb = c - 512;
                int row = cb >> 2, sl = cb & 3;
                const short* src = &Wbf[(size_t)row * 384 + kt + ((sl ^ ((row >> 1) & 3)) * 8)];
                GL2LDS16(src, &Bs[buf][(g - 8) * 512]);
            }
        }
    };
    auto compute = [&](int buf) {
        bf16x8 af[4], bfr[2];
#pragma unroll
        for (int fi = 0; fi < 4; ++fi) {
            int row = wr * 64 + fi * 16 + lr;
            af[fi] = *(const bf16x8*)&As[buf][row * 32 + ((lk ^ ((row >> 1) & 3)) * 8)];
        }
#pragma unroll
        for (int fj = 0; fj < 2; ++fj) {
            int row = wc * 32 + fj * 16 + lr;
            bfr[fj] = *(const bf16x8*)&Bs[buf][row * 32 + ((lk ^ ((row >> 1) & 3)) * 8)];
        }
#pragma unroll
        for (int fi = 0; fi < 4; ++fi)
#pragma unroll
            for (int fj = 0; fj < 2; ++fj)
                acc[fi][fj] = __builtin_amdgcn_mfma_f32_16x16x32_bf16(af[fi], bfr[fj], acc[fi][fj], 0, 0, 0);
    };

    issue(0, 0);
    __syncthreads();
#pragma unroll
    for (int tgt = 0; tgt < 12; ++tgt) {
        if (tgt < 11) issue((tgt + 1) & 1, (tgt + 1) * 32);  // async DMA into other buffer
        compute(tgt & 1);                                     // hides the DMA
        __syncthreads();                                      // reads done + loads landed
    }

    // epilogue: C row = lk*4+reg, col = lr
#pragma unroll
    for (int fi = 0; fi < 4; ++fi) {
#pragma unroll
        for (int reg = 0; reg < 4; ++reg) {
            int gm = m0 + wr * 64 + fi * 16 + lk * 4 + reg;
            if (gm >= M) continue;
#pragma unroll
            for (int fj = 0; fj < 2; ++fj) {
                int gn = wc * 32 + fj * 16 + lr;
                float y = acc[fi][fj][reg] + bias[gn];
                y = fmaxf(y, 0.f);
                if (mode == 2) {
                    float sc = rsqrtf(bnv[gn] + 1e-5f) * bng[gn];
                    y = (y - bnm[gn]) * sc + bnb[gn];
                } else {
                    y += bf2f(res[(size_t)gm * 128 + gn]);
                }
                out[(size_t)gm * 128 + gn] = f2bf(y);
            }
        }
    }
}

// ---------------- fused MLP: out[M][64] = relu(x@Wm1^T+bm1) @ Wm2^T + bm2 ----------------

#define LDP 40

static __global__ __launch_bounds__(256) void k_mlp(
    const short* __restrict__ X, const short* __restrict__ Wm1bf, const float* __restrict__ bm1,
    const short* __restrict__ Wm2bf, const float* __restrict__ bm2,
    int M, float* __restrict__ out) {
    __shared__ short As[64 * LDP];       // phase1 A tile / phase2 B tile
    __shared__ short Bs[128 * LDP];      // phase1 Wm1 tile
    __shared__ short hs[64 * 136];       // h, padded stride 136

    const int t = threadIdx.x;
    const int m0 = blockIdx.x * 64;
    const int w  = t >> 6;
    const int wr = w >> 1;
    const int wc = w & 1;
    const int l  = t & 63;
    const int lr = l & 15;
    const int lk = l >> 4;

    f32x4 acc1[2][4];
#pragma unroll
    for (int i = 0; i < 2; ++i)
#pragma unroll
        for (int j = 0; j < 4; ++j) acc1[i][j] = (f32x4){0.f, 0.f, 0.f, 0.f};

    for (int kt = 0; kt < 128; kt += 32) {
        {
            int row = t >> 2;
            int slot = t & 3;
            int gm = m0 + row;
            bf16x8 v = {0, 0, 0, 0, 0, 0, 0, 0};
            if (gm < M) v = *(const bf16x8*)&X[(size_t)gm * 128 + kt + slot * 8];
            *(bf16x8*)&As[row * LDP + slot * 8] = v;
        }
#pragma unroll
        for (int it = 0; it < 2; ++it) {
            int idx = it * 256 + t;
            int row = idx >> 2;
            int slot = idx & 3;
            bf16x8 v = *(const bf16x8*)&Wm1bf[(size_t)row * 128 + kt + slot * 8];
            *(bf16x8*)&Bs[row * LDP + slot * 8] = v;
        }
        __syncthreads();

        bf16x8 af[2], bfr[4];
#pragma unroll
        for (int fi = 0; fi < 2; ++fi)
            af[fi] = *(const bf16x8*)&As[(wr * 32 + fi * 16 + lr) * LDP + lk * 8];
#pragma unroll
        for (int fj = 0; fj < 4; ++fj)
            bfr[fj] = *(const bf16x8*)&Bs[(wc * 64 + fj * 16 + lr) * LDP + lk * 8];
#pragma unroll
        for (int fi = 0; fi < 2; ++fi)
#pragma unroll
            for (int fj = 0; fj < 4; ++fj)
                acc1[fi][fj] = __builtin_amdgcn_mfma_f32_16x16x32_bf16(af[fi], bfr[fj], acc1[fi][fj], 0, 0, 0);
        __syncthreads();
    }

#pragma unroll
    for (int fi = 0; fi < 2; ++fi) {
#pragma unroll
        for (int reg = 0; reg < 4; ++reg) {
            int rloc = wr * 32 + fi * 16 + lk * 4 + reg;
#pragma unroll
            for (int fj = 0; fj < 4; ++fj) {
                int col = wc * 64 + fj * 16 + lr;
                float y = acc1[fi][fj][reg] + bm1[col];
                hs[rloc * 136 + col] = f2bf(fmaxf(y, 0.f));
            }
        }
    }
    __syncthreads();

    f32x4 acc2[2][2];
#pragma unroll
    for (int i = 0; i < 2; ++i)
#pragma unroll
        for (int j = 0; j < 2; ++j) acc2[i][j] = (f32x4){0.f, 0.f, 0.f, 0.f};

    for (int kt = 0; kt < 128; kt += 32) {
        {
            int row = t >> 2;
            int slot = t & 3;
            bf16x8 v = *(const bf16x8*)&Wm2bf[(size_t)row * 128 + kt + slot * 8];
            *(bf16x8*)&As[row * LDP + slot * 8] = v;
        }
        __syncthreads();

        bf16x8 af[2], bfr[2];
#pragma unroll
        for (int fi = 0; fi < 2; ++fi)
            af[fi] = *(const bf16x8*)&hs[(wr * 32 + fi * 16 + lr) * 136 + kt + lk * 8];
#pragma unroll
        for (int fj = 0; fj < 2; ++fj)
            bfr[fj] = *(const bf16x8*)&As[(wc * 32 + fj * 16 + lr) * LDP + lk * 8];
#pragma unroll
        for (int fi = 0; fi < 2; ++fi)
#pragma unroll
            for (int fj = 0; fj < 2; ++fj)
                acc2[fi][fj] = __builtin_amdgcn_mfma_f32_16x16x32_bf16(af[fi], bfr[fj], acc2[fi][fj], 0, 0, 0);
        __syncthreads();
    }

#pragma unroll
    for (int fi = 0; fi < 2; ++fi) {
#pragma unroll
        for (int reg = 0; reg < 4; ++reg) {
            int gm = m0 + wr * 32 + fi * 16 + lk * 4 + reg;
            if (gm >= M) continue;
#pragma unroll
            for (int fj = 0; fj < 2; ++fj) {
                int gn = wc * 32 + fj * 16 + lr;
                out[(size_t)gm * 64 + gn] = acc2[fi][fj][reg] + bm2[gn];
            }
        }
    }
}

// ---------------- launch ----------------

extern "C" void kernel_launch(void* const* d_in, const int* in_sizes, int n_in,
                              void* d_out, int out_size, void* d_ws, size_t ws_size,
                              hipStream_t stream) {
    const float* features = (const float*)d_in[0];
    const int*   esrc     = (const int*)d_in[1];
    const int*   edst     = (const int*)d_in[2];
    const float* W1   = (const float*)d_in[3];
    const float* b1   = (const float*)d_in[4];
    const float* bng  = (const float*)d_in[5];
    const float* bnb  = (const float*)d_in[6];
    const float* bnm  = (const float*)d_in[7];
    const float* bnv  = (const float*)d_in[8];
    const float* W3   = (const float*)d_in[9];
    const float* b3   = (const float*)d_in[10];
    const float* Wm1  = (const float*)d_in[11];
    const float* bm1  = (const float*)d_in[12];
    const float* Wm2  = (const float*)d_in[13];
    const float* bm2  = (const float*)d_in[14];
    float* out = (float*)d_out;

    const int n  = in_sizes[0] / NF;     // 100000
    const int ne = in_sizes[1];          // 600000

    uint8_t* w = (uint8_t*)d_ws;
    size_t off = 0;
    auto alloc = [&](size_t bytes) -> void* {
        void* p = w + off;
        off = (off + bytes + 255) & ~(size_t)255;
        return p;
    };
    float* dinv   = (float*)alloc((size_t)n * 4);
    int* counts   = (int*)alloc((size_t)n * 4);
    int* row_off  = (int*)alloc(((size_t)n + 1) * 4);
    int* cursor   = (int*)alloc((size_t)n * 4);
    int* csr      = (int*)alloc((size_t)ne * 4);
    int* bsum     = (int*)alloc(4096);
    short* fbf    = (short*)alloc((size_t)n * NF * 2);
    short* bufB   = (short*)alloc((size_t)n * NF * 2);
    short* bufC   = (short*)alloc((size_t)n * NF * 2);
    short* bufD   = (short*)alloc((size_t)n * NF * 2);
    short* bufE   = (short*)alloc((size_t)n * NF * 2);
    short* W1bf   = (short*)alloc((size_t)128 * 384 * 2);
    short* W3bf   = (short*)alloc((size_t)128 * 384 * 2);
    short* Wm1bf  = (short*)alloc((size_t)128 * 128 * 2);
    short* Wm2bf  = (short*)alloc((size_t)64 * 128 * 2);
    (void)ws_size;

    const int TB = 256;
    const int nbE = (ne + TB - 1) / TB;
    const int nbN = (n + TB - 1) / TB;
    const int n8  = n * NF / 8;
    const int nbF = (n8 + TB - 1) / TB;

    hipMemsetAsync(counts, 0, (size_t)n * 4, stream);
    k_pro<<<nbE + nbF + 60, TB, 0, stream>>>(edst, ne, counts,
                                             features, fbf, n8, nbE, nbF,
                                             W1, W3, Wm1, Wm2, W1bf, W3bf, Wm1bf, Wm2bf);
    k_scan1<<<nbN, SCAN_B, 0, stream>>>(counts, n, row_off, bsum);
    k_scan2<<<1, 512, 0, stream>>>(bsum, nbN);
    k_scan3<<<nbN, SCAN_B, 0, stream>>>(row_off, bsum, n, ne, cursor, counts, dinv);
    k_fill<<<nbE, TB, 0, stream>>>(esrc, edst, ne, cursor, csr);

    const int gm128 = (n + 127) / 128;
    const int gm64  = (n + 63) / 64;
    const int nbL   = (n + 3) / 4;   // lap: 4 nodes per 256-thread block

    // ---- conv1 ----
    k_lap<<<nbL, 256, 0, stream>>>(fbf, nullptr, row_off, csr, dinv, 1.f, -1.f, 0.f, bufB, n);
    k_lap<<<nbL, 256, 0, stream>>>(bufB, fbf, row_off, csr, dinv, 2.f, -2.f, -1.f, bufC, n);
    k_gemm_conv<<<gm128, 512, 0, stream>>>(fbf, bufB, bufC, W1bf, b1,
                                           nullptr, bng, bnb, bnm, bnv, n, 2, bufD);

    // ---- conv2 ----
    k_lap<<<nbL, 256, 0, stream>>>(bufD, nullptr, row_off, csr, dinv, 1.f, -1.f, 0.f, bufB, n);
    k_lap<<<nbL, 256, 0, stream>>>(bufB, bufD, row_off, csr, dinv, 2.f, -2.f, -1.f, bufC, n);
    k_gemm_conv<<<gm128, 512, 0, stream>>>(bufD, bufB, bufC, W3bf, b3,
                                           bufD, nullptr, nullptr, nullptr, nullptr, n, 3, bufE);

    // ---- fused MLP ----
    k_mlp<<<gm64, 256, 0, stream>>>(bufE, Wm1bf, bm1, Wm2bf, bm2, n, out);
}

// Round 14
// 317.503 us; speedup vs baseline: 1.0989x; 1.0467x over previous
//
#include <hip/hip_runtime.h>
#include <cstdint>
#include <cstddef>

#define NF 128          // feature width (IN_F == HID_F == 128)
#define SCAN_B 256

typedef __attribute__((ext_vector_type(4))) float f32x4;
typedef __attribute__((ext_vector_type(8))) short bf16x8;

#define GL2LDS16(g, l) __builtin_amdgcn_global_load_lds(                     \
    (const __attribute__((address_space(1))) unsigned*)(g),                  \
    (__attribute__((address_space(3))) unsigned*)(l), 16, 0, 0)

static __device__ inline float bf2f(short u) {
    union { unsigned u; float f; } v;
    v.u = ((unsigned)(unsigned short)u) << 16;
    return v.f;
}
static __device__ inline short f2bf(float f) {
    union { float f; unsigned u; } v; v.f = f;
    unsigned r = v.u + 0x7FFF + ((v.u >> 16) & 1);  // RNE
    return (short)(r >> 16);
}
static __device__ inline float u2f(unsigned u) {
    union { unsigned u; float f; } v; v.u = u; return v.f;
}
static __device__ inline unsigned f2u(float f) {
    union { float f; unsigned u; } v; v.f = f; return v.u;
}
static __device__ inline unsigned packbf(float lo, float hi) {
    unsigned ul = f2u(lo), uh = f2u(hi);
    ul = ul + 0x7FFF + ((ul >> 16) & 1);
    uh = uh + 0x7FFF + ((uh >> 16) & 1);
    return (ul >> 16) | (uh & 0xFFFF0000u);
}

// ---------------- fused prologue: edge-count + feature cvt + weight FOLD/cvt ----------------
// Chebyshev weight folding (pure-aggregation laps):
//   Y = X0(W0-W1+W2)^T + Z1(W1-4W2)^T + Z2'(2W2)^T   with Z1=P X0, Z2'=P Z1.
// block roles: [0, nbE) count | [nbE, nbE+nbF) feature cvt | [nbE+nbF, +60) weight fold/cvt

static __global__ __launch_bounds__(256) void k_pro(
    const int* __restrict__ dst, int ne, int* __restrict__ counts,
    const float* __restrict__ feat, short* __restrict__ fbf, int n8, int nbE, int nbF,
    const float* __restrict__ w1, const float* __restrict__ w3,
    const float* __restrict__ wm1, const float* __restrict__ wm2,
    short* __restrict__ o1, short* __restrict__ o3,
    short* __restrict__ om1, short* __restrict__ om2) {
    int b = blockIdx.x;
    if (b < nbE) {
        int e = b * 256 + threadIdx.x;
        if (e < ne) atomicAdd(&counts[dst[e]], 1);
        return;
    }
    b -= nbE;
    if (b < nbF) {
        int i = b * 256 + threadIdx.x;
        if (i < n8) {
            f32x4 a = *(const f32x4*)&feat[(size_t)i * 8];
            f32x4 c = *(const f32x4*)&feat[(size_t)i * 8 + 4];
            bf16x8 r;
            r[0] = f2bf(a[0]); r[1] = f2bf(a[1]); r[2] = f2bf(a[2]); r[3] = f2bf(a[3]);
            r[4] = f2bf(c[0]); r[5] = f2bf(c[1]); r[6] = f2bf(c[2]); r[7] = f2bf(c[3]);
            *(bf16x8*)&fbf[(size_t)i * 8] = r;
        }
        return;
    }
    b -= nbF;
    int i = b * 256 + threadIdx.x;   // 0..15359
    if (i < 12288) {
        // fold W1 (i<6144) or W3: item = one 8-float chunk of the folded [128][384]
        const float* x = (i < 6144) ? w1 : w3;
        short* y       = (i < 6144) ? o1 : o3;
        int ii = (i < 6144) ? i : i - 6144;
        int r = ii / 48, c = ii % 48;
        int kt = c * 8, seg = kt >> 7, o = kt & 127;
        const float* base = x + (size_t)r * 384;
        float c0, c1, c2;
        if (seg == 0)      { c0 = 1.f;  c1 = -1.f; c2 = 1.f;  }
        else if (seg == 1) { c0 = 0.f;  c1 = 1.f;  c2 = -4.f; }
        else               { c0 = 0.f;  c1 = 0.f;  c2 = 2.f;  }
        bf16x8 rr;
#pragma unroll
        for (int h = 0; h < 2; ++h) {
            f32x4 a0 = *(const f32x4*)&base[o + h * 4];
            f32x4 a1 = *(const f32x4*)&base[128 + o + h * 4];
            f32x4 a2 = *(const f32x4*)&base[256 + o + h * 4];
#pragma unroll
            for (int j = 0; j < 4; ++j)
                rr[h * 4 + j] = f2bf(c0 * a0[j] + c1 * a1[j] + c2 * a2[j]);
        }
        *(bf16x8*)&y[(size_t)r * 384 + kt] = rr;
        return;
    }
    // plain convert Wm1 / Wm2
    const float* x; short* y; int off;
    if (i < 14336) { x = wm1; y = om1; off = i - 12288; }
    else           { x = wm2; y = om2; off = i - 14336; }
    f32x4 a = *(const f32x4*)&x[(size_t)off * 8];
    f32x4 c = *(const f32x4*)&x[(size_t)off * 8 + 4];
    bf16x8 r;
    r[0] = f2bf(a[0]); r[1] = f2bf(a[1]); r[2] = f2bf(a[2]); r[3] = f2bf(a[3]);
    r[4] = f2bf(c[0]); r[5] = f2bf(c[1]); r[6] = f2bf(c[2]); r[7] = f2bf(c[3]);
    *(bf16x8*)&y[(size_t)off * 8] = r;
}

// ---------------- scans ----------------

static __global__ void k_scan1(const int* __restrict__ counts, int n,
                               int* __restrict__ row_off, int* __restrict__ bsum) {
    __shared__ int s[SCAN_B];
    int t = threadIdx.x;
    int base = blockIdx.x * SCAN_B;
    int v = (base + t < n) ? counts[base + t] : 0;
    s[t] = v;
    __syncthreads();
    for (int off = 1; off < SCAN_B; off <<= 1) {
        int x = 0;
        if (t >= off) x = s[t - off];
        __syncthreads();
        if (t >= off) s[t] += x;
        __syncthreads();
    }
    if (base + t < n) row_off[base + t] = s[t] - v;
    if (t == SCAN_B - 1) bsum[blockIdx.x] = s[t];
}

static __global__ void k_scan2(int* __restrict__ bsum, int nb) {
    __shared__ int s[512];
    int t = threadIdx.x;
    int v = (t < nb) ? bsum[t] : 0;
    s[t] = v;
    __syncthreads();
    for (int off = 1; off < 512; off <<= 1) {
        int x = 0;
        if (t >= off) x = s[t - off];
        __syncthreads();
        if (t >= off) s[t] += x;
        __syncthreads();
    }
    if (t < nb) bsum[t] = s[t] - v;
}

// scan3 + dinv fused
static __global__ void k_scan3(int* __restrict__ row_off, const int* __restrict__ bsum,
                               int n, int ne, int* __restrict__ cursor,
                               const int* __restrict__ counts, float* __restrict__ dinv) {
    int i = blockIdx.x * SCAN_B + threadIdx.x;
    if (i < n) {
        int v = row_off[i] + bsum[blockIdx.x];
        row_off[i] = v;
        cursor[i] = v;
        float d = fmaxf((float)counts[i], 1.0f);
        dinv[i] = rsqrtf(d);
    }
    if (i == 0) row_off[n] = ne;
}

static __global__ void k_fill(const int* __restrict__ src, const int* __restrict__ dst, int ne,
                              int* __restrict__ cursor, int* __restrict__ csr) {
    int e = blockIdx.x * blockDim.x + threadIdx.x;
    if (e < ne) {
        int d = dst[e];
        int p = atomicAdd(&cursor[d], 1);
        csr[p] = src[e];
    }
}

// ---------------- pure aggregation: out = dinv_i * sum_src Xin[src]*dinv[src] ----------------
// One wave per node; lane l owns edge e0+l (index + dinv in one coalesced round);
// readlane broadcast -> SGPR base addressing. No self-read, no axpy (weights folded).

static __global__ __launch_bounds__(256) void k_lap(
    const short* __restrict__ Xin,
    const int* __restrict__ row_off, const int* __restrict__ csr,
    const float* __restrict__ dinv,
    short* __restrict__ out, int n) {
    int node = blockIdx.x * 4 + (threadIdx.x >> 6);
    if (node >= n) return;
    int l = threadIdx.x & 63;
    const unsigned* Xu = (const unsigned*)Xin;
    int e0 = row_off[node], e1 = row_off[node + 1];
    int deg = e1 - e0;

    int myi = 0;
    float mydv = 0.f;
    if (l < deg && l < 64) {
        myi = csr[e0 + l];
        mydv = dinv[myi];
    }

    float s0 = 0.f, s1 = 0.f;
    int dcap = deg < 64 ? deg : 64;
    for (int base = 0; base < dcap; base += 8) {
        unsigned v[8]; float dv[8];
#pragma unroll
        for (int j = 0; j < 8; ++j) {
            int jj = base + j;
            bool act = (jj < dcap);                       // wave-uniform
            int lane = act ? jj : base;                   // masked -> base edge's row (L1-hot)
            int src = __builtin_amdgcn_readlane(myi, lane);
            unsigned dvb = __builtin_amdgcn_readlane((int)f2u(mydv), lane);
            dv[j] = act ? u2f(dvb) : 0.f;
            v[j] = Xu[(size_t)src * 64 + l];
        }
#pragma unroll
        for (int j = 0; j < 8; ++j) {
            s0 += u2f(v[j] << 16) * dv[j];
            s1 += u2f(v[j] & 0xFFFF0000u) * dv[j];
        }
    }
    // rare tail: degree > 64
    for (int base = e0 + 64; base < e1; base += 8) {
        int m = e1 - base;
        int idx = 0;
        if (l < 8 && l < m) idx = csr[base + l];
        unsigned v[8]; float dv[8];
#pragma unroll
        for (int j = 0; j < 8; ++j) {
            int src = __shfl(idx, j, 64);
            bool act = (j < m);
            if (!act) src = 0;
            dv[j] = act ? dinv[src] : 0.f;
            v[j] = Xu[(size_t)src * 64 + l];
        }
#pragma unroll
        for (int j = 0; j < 8; ++j) {
            s0 += u2f(v[j] << 16) * dv[j];
            s1 += u2f(v[j] & 0xFFFF0000u) * dv[j];
        }
    }

    float di = dinv[node];
    ((unsigned*)out)[(size_t)node * 64 + l] = packbf(s0 * di, s1 * di);
}

// ---------------- conv GEMM (R11 structure, ~46us floor) ----------------
// out[M][128] = concat(X0, Z1, Z2')[M][384] @ Wfold[128][384]^T  (+epilogue)
// BM=128, BN=128, BK=32, 512 threads = 8 waves (2x4), wave tile 64x32, frag 4x2.
// gload_lds 16B staging, double-buffered, ONE barrier per K-step.
// Bank conflicts: slot XOR (row>>1)&3 on BOTH source and ds_read (rule #21).
// mode 2: bn(relu(y+b))   mode 3: relu(y+b)+res.  Output bf16.

static __global__ __launch_bounds__(512) void k_gemm_conv(
    const short* __restrict__ X0, const short* __restrict__ X1, const short* __restrict__ X2,
    const short* __restrict__ Wbf, const float* __restrict__ bias,
    const short* __restrict__ res,
    const float* __restrict__ bng, const float* __restrict__ bnb,
    const float* __restrict__ bnm, const float* __restrict__ bnv,
    int M, int mode, short* __restrict__ out) {
    __shared__ short As[2][128 * 32];
    __shared__ short Bs[2][128 * 32];

    // bijective XCD swizzle (m204)
    const int nwg = gridDim.x;
    const int q = nwg >> 3, r = nwg & 7;
    const int xcd = blockIdx.x & 7, slot = blockIdx.x >> 3;
    const int flat = (xcd < r ? xcd * (q + 1) : r * (q + 1) + (xcd - r) * q) + slot;
    const int m0 = flat * 128;

    const int t = threadIdx.x;
    const int wv = t >> 6;          // 0..7
    const int ln = t & 63;
    const int wr = wv >> 2;         // 0..1 (M)
    const int wc = wv & 3;          // 0..3 (N)
    const int lr = ln & 15;
    const int lk = ln >> 4;

    const short* segs[3] = {X0, X1, X2};

    f32x4 acc[4][2];
#pragma unroll
    for (int i = 0; i < 4; ++i)
#pragma unroll
        for (int j = 0; j < 2; ++j) acc[i][j] = (f32x4){0.f, 0.f, 0.f, 0.f};

    auto issue = [&](int buf, int kt) {
        const short* Xp = segs[kt >> 7];
        const int klocal = kt & 127;
#pragma unroll
        for (int j = 0; j < 2; ++j) {
            int g = wv * 2 + j;            // 0..15
            int c = g * 64 + ln;
            if (g < 8) {
                int row = c >> 2, sl = c & 3;
                int gm = m0 + row;
                if (gm > M - 1) gm = M - 1;   // clamp: valid addr, row unused in epilogue
                const short* src = &Xp[(size_t)gm * 128 + klocal + ((sl ^ ((row >> 1) & 3)) * 8)];
                GL2LDS16(src, &As[buf][g * 512]);
            } else {
                int cb = c - 512;
                int row = cb >> 2, sl = cb & 3;
                const short* src = &Wbf[(size_t)row * 384 + kt + ((sl ^ ((row >> 1) & 3)) * 8)];
                GL2LDS16(src, &Bs[buf][(g - 8) * 512]);
            }
        }
    };
    auto compute = [&](int buf) {
        bf16x8 af[4], bfr[2];
#pragma unroll
        for (int fi = 0; fi < 4; ++fi) {
            int row = wr * 64 + fi * 16 + lr;
            af[fi] = *(const bf16x8*)&As[buf][row * 32 + ((lk ^ ((row >> 1) & 3)) * 8)];
        }
#pragma unroll
        for (int fj = 0; fj < 2; ++fj) {
            int row = wc * 32 + fj * 16 + lr;
            bfr[fj] = *(const bf16x8*)&Bs[buf][row * 32 + ((lk ^ ((row >> 1) & 3)) * 8)];
        }
#pragma unroll
        for (int fi = 0; fi < 4; ++fi)
#pragma unroll
            for (int fj = 0; fj < 2; ++fj)
                acc[fi][fj] = __builtin_amdgcn_mfma_f32_16x16x32_bf16(af[fi], bfr[fj], acc[fi][fj], 0, 0, 0);
    };

    issue(0, 0);
    __syncthreads();
#pragma unroll
    for (int tgt = 0; tgt < 12; ++tgt) {
        if (tgt < 11) issue((tgt + 1) & 1, (tgt + 1) * 32);  // async DMA into other buffer
        compute(tgt & 1);                                     // hides the DMA
        __syncthreads();                                      // reads done + loads landed
    }

    // epilogue: C row = lk*4+reg, col = lr
#pragma unroll
    for (int fi = 0; fi < 4; ++fi) {
#pragma unroll
        for (int reg = 0; reg < 4; ++reg) {
            int gm = m0 + wr * 64 + fi * 16 + lk * 4 + reg;
            if (gm >= M) continue;
#pragma unroll
            for (int fj = 0; fj < 2; ++fj) {
                int gn = wc * 32 + fj * 16 + lr;
                float y = acc[fi][fj][reg] + bias[gn];
                y = fmaxf(y, 0.f);
                if (mode == 2) {
                    float sc = rsqrtf(bnv[gn] + 1e-5f) * bng[gn];
                    y = (y - bnm[gn]) * sc + bnb[gn];
                } else {
                    y += bf2f(res[(size_t)gm * 128 + gn]);
                }
                out[(size_t)gm * 128 + gn] = f2bf(y);
            }
        }
    }
}

// ---------------- fused MLP: out[M][64] = relu(x@Wm1^T+bm1) @ Wm2^T + bm2 ----------------

#define LDP 40

static __global__ __launch_bounds__(256) void k_mlp(
    const short* __restrict__ X, const short* __restrict__ Wm1bf, const float* __restrict__ bm1,
    const short* __restrict__ Wm2bf, const float* __restrict__ bm2,
    int M, float* __restrict__ out) {
    __shared__ short As[64 * LDP];       // phase1 A tile / phase2 B tile
    __shared__ short Bs[128 * LDP];      // phase1 Wm1 tile
    __shared__ short hs[64 * 136];       // h, padded stride 136

    const int t = threadIdx.x;
    const int m0 = blockIdx.x * 64;
    const int w  = t >> 6;
    const int wr = w >> 1;
    const int wc = w & 1;
    const int l  = t & 63;
    const int lr = l & 15;
    const int lk = l >> 4;

    f32x4 acc1[2][4];
#pragma unroll
    for (int i = 0; i < 2; ++i)
#pragma unroll
        for (int j = 0; j < 4; ++j) acc1[i][j] = (f32x4){0.f, 0.f, 0.f, 0.f};

    for (int kt = 0; kt < 128; kt += 32) {
        {
            int row = t >> 2;
            int slot = t & 3;
            int gm = m0 + row;
            bf16x8 v = {0, 0, 0, 0, 0, 0, 0, 0};
            if (gm < M) v = *(const bf16x8*)&X[(size_t)gm * 128 + kt + slot * 8];
            *(bf16x8*)&As[row * LDP + slot * 8] = v;
        }
#pragma unroll
        for (int it = 0; it < 2; ++it) {
            int idx = it * 256 + t;
            int row = idx >> 2;
            int slot = idx & 3;
            bf16x8 v = *(const bf16x8*)&Wm1bf[(size_t)row * 128 + kt + slot * 8];
            *(bf16x8*)&Bs[row * LDP + slot * 8] = v;
        }
        __syncthreads();

        bf16x8 af[2], bfr[4];
#pragma unroll
        for (int fi = 0; fi < 2; ++fi)
            af[fi] = *(const bf16x8*)&As[(wr * 32 + fi * 16 + lr) * LDP + lk * 8];
#pragma unroll
        for (int fj = 0; fj < 4; ++fj)
            bfr[fj] = *(const bf16x8*)&Bs[(wc * 64 + fj * 16 + lr) * LDP + lk * 8];
#pragma unroll
        for (int fi = 0; fi < 2; ++fi)
#pragma unroll
            for (int fj = 0; fj < 4; ++fj)
                acc1[fi][fj] = __builtin_amdgcn_mfma_f32_16x16x32_bf16(af[fi], bfr[fj], acc1[fi][fj], 0, 0, 0);
        __syncthreads();
    }

#pragma unroll
    for (int fi = 0; fi < 2; ++fi) {
#pragma unroll
        for (int reg = 0; reg < 4; ++reg) {
            int rloc = wr * 32 + fi * 16 + lk * 4 + reg;
#pragma unroll
            for (int fj = 0; fj < 4; ++fj) {
                int col = wc * 64 + fj * 16 + lr;
                float y = acc1[fi][fj][reg] + bm1[col];
                hs[rloc * 136 + col] = f2bf(fmaxf(y, 0.f));
            }
        }
    }
    __syncthreads();

    f32x4 acc2[2][2];
#pragma unroll
    for (int i = 0; i < 2; ++i)
#pragma unroll
        for (int j = 0; j < 2; ++j) acc2[i][j] = (f32x4){0.f, 0.f, 0.f, 0.f};

    for (int kt = 0; kt < 128; kt += 32) {
        {
            int row = t >> 2;
            int slot = t & 3;
            bf16x8 v = *(const bf16x8*)&Wm2bf[(size_t)row * 128 + kt + slot * 8];
            *(bf16x8*)&As[row * LDP + slot * 8] = v;
        }
        __syncthreads();

        bf16x8 af[2], bfr[2];
#pragma unroll
        for (int fi = 0; fi < 2; ++fi)
            af[fi] = *(const bf16x8*)&hs[(wr * 32 + fi * 16 + lr) * 136 + kt + lk * 8];
#pragma unroll
        for (int fj = 0; fj < 2; ++fj)
            bfr[fj] = *(const bf16x8*)&As[(wc * 32 + fj * 16 + lr) * LDP + lk * 8];
#pragma unroll
        for (int fi = 0; fi < 2; ++fi)
#pragma unroll
            for (int fj = 0; fj < 2; ++fj)
                acc2[fi][fj] = __builtin_amdgcn_mfma_f32_16x16x32_bf16(af[fi], bfr[fj], acc2[fi][fj], 0, 0, 0);
        __syncthreads();
    }

#pragma unroll
    for (int fi = 0; fi < 2; ++fi) {
#pragma unroll
        for (int reg = 0; reg < 4; ++reg) {
            int gm = m0 + wr * 32 + fi * 16 + lk * 4 + reg;
            if (gm >= M) continue;
#pragma unroll
            for (int fj = 0; fj < 2; ++fj) {
                int gn = wc * 32 + fj * 16 + lr;
                out[(size_t)gm * 64 + gn] = acc2[fi][fj][reg] + bm2[gn];
            }
        }
    }
}

// ---------------- launch ----------------

extern "C" void kernel_launch(void* const* d_in, const int* in_sizes, int n_in,
                              void* d_out, int out_size, void* d_ws, size_t ws_size,
                              hipStream_t stream) {
    const float* features = (const float*)d_in[0];
    const int*   esrc     = (const int*)d_in[1];
    const int*   edst     = (const int*)d_in[2];
    const float* W1   = (const float*)d_in[3];
    const float* b1   = (const float*)d_in[4];
    const float* bng  = (const float*)d_in[5];
    const float* bnb  = (const float*)d_in[6];
    const float* bnm  = (const float*)d_in[7];
    const float* bnv  = (const float*)d_in[8];
    const float* W3   = (const float*)d_in[9];
    const float* b3   = (const float*)d_in[10];
    const float* Wm1  = (const float*)d_in[11];
    const float* bm1  = (const float*)d_in[12];
    const float* Wm2  = (const float*)d_in[13];
    const float* bm2  = (const float*)d_in[14];
    float* out = (float*)d_out;

    const int n  = in_sizes[0] / NF;     // 100000
    const int ne = in_sizes[1];          // 600000

    uint8_t* w = (uint8_t*)d_ws;
    size_t off = 0;
    auto alloc = [&](size_t bytes) -> void* {
        void* p = w + off;
        off = (off + bytes + 255) & ~(size_t)255;
        return p;
    };
    float* dinv   = (float*)alloc((size_t)n * 4);
    int* counts   = (int*)alloc((size_t)n * 4);
    int* row_off  = (int*)alloc(((size_t)n + 1) * 4);
    int* cursor   = (int*)alloc((size_t)n * 4);
    int* csr      = (int*)alloc((size_t)ne * 4);
    int* bsum     = (int*)alloc(4096);
    short* fbf    = (short*)alloc((size_t)n * NF * 2);
    short* bufB   = (short*)alloc((size_t)n * NF * 2);   // Z1
    short* bufC   = (short*)alloc((size_t)n * NF * 2);   // Z2'
    short* bufD   = (short*)alloc((size_t)n * NF * 2);   // h1 (conv1 out, residual)
    short* bufE   = (short*)alloc((size_t)n * NF * 2);   // conv2 out
    short* W1bf   = (short*)alloc((size_t)128 * 384 * 2);  // folded
    short* W3bf   = (short*)alloc((size_t)128 * 384 * 2);  // folded
    short* Wm1bf  = (short*)alloc((size_t)128 * 128 * 2);
    short* Wm2bf  = (short*)alloc((size_t)64 * 128 * 2);
    (void)ws_size;

    const int TB = 256;
    const int nbE = (ne + TB - 1) / TB;
    const int nbN = (n + TB - 1) / TB;
    const int n8  = n * NF / 8;
    const int nbF = (n8 + TB - 1) / TB;

    hipMemsetAsync(counts, 0, (size_t)n * 4, stream);
    k_pro<<<nbE + nbF + 60, TB, 0, stream>>>(edst, ne, counts,
                                             features, fbf, n8, nbE, nbF,
                                             W1, W3, Wm1, Wm2, W1bf, W3bf, Wm1bf, Wm2bf);
    k_scan1<<<nbN, SCAN_B, 0, stream>>>(counts, n, row_off, bsum);
    k_scan2<<<1, 512, 0, stream>>>(bsum, nbN);
    k_scan3<<<nbN, SCAN_B, 0, stream>>>(row_off, bsum, n, ne, cursor, counts, dinv);
    k_fill<<<nbE, TB, 0, stream>>>(esrc, edst, ne, cursor, csr);

    const int gm128 = (n + 127) / 128;
    const int gm64  = (n + 63) / 64;
    const int nbL   = (n + 3) / 4;   // lap: 4 nodes per 256-thread block

    // ---- conv1:  Z1 = P X0;  Z2' = P Z1;  Y = [X0|Z1|Z2'] @ W1fold^T ----
    k_lap<<<nbL, 256, 0, stream>>>(fbf, row_off, csr, dinv, bufB, n);
    k_lap<<<nbL, 256, 0, stream>>>(bufB, row_off, csr, dinv, bufC, n);
    k_gemm_conv<<<gm128, 512, 0, stream>>>(fbf, bufB, bufC, W1bf, b1,
                                           nullptr, bng, bnb, bnm, bnv, n, 2, bufD);

    // ---- conv2 ----
    k_lap<<<nbL, 256, 0, stream>>>(bufD, row_off, csr, dinv, bufB, n);
    k_lap<<<nbL, 256, 0, stream>>>(bufB, row_off, csr, dinv, bufC, n);
    k_gemm_conv<<<gm128, 512, 0, stream>>>(bufD, bufB, bufC, W3bf, b3,
                                           bufD, nullptr, nullptr, nullptr, nullptr, n, 3, bufE);

    // ---- fused MLP ----
    k_mlp<<<gm64, 256, 0, stream>>>(bufE, Wm1bf, bm1, Wm2bf, bm2, n, out);
}

// Round 15
// 283.184 us; speedup vs baseline: 1.2320x; 1.1212x over previous
//
#include <hip/hip_runtime.h>
#include <cstdint>
#include <cstddef>

#define NF 128          // feature width (IN_F == HID_F == 128)
#define SCAN_B 256

typedef __attribute__((ext_vector_type(4))) float f32x4;
typedef __attribute__((ext_vector_type(8))) short bf16x8;

#define GL2LDS16(g, l) __builtin_amdgcn_global_load_lds(                     \
    (const __attribute__((address_space(1))) unsigned*)(g),                  \
    (__attribute__((address_space(3))) unsigned*)(l), 16, 0, 0)

static __device__ inline float bf2f(short u) {
    union { unsigned u; float f; } v;
    v.u = ((unsigned)(unsigned short)u) << 16;
    return v.f;
}
static __device__ inline short f2bf(float f) {
    union { float f; unsigned u; } v; v.f = f;
    unsigned r = v.u + 0x7FFF + ((v.u >> 16) & 1);  // RNE
    return (short)(r >> 16);
}
static __device__ inline float u2f(unsigned u) {
    union { unsigned u; float f; } v; v.u = u; return v.f;
}
static __device__ inline unsigned f2u(float f) {
    union { float f; unsigned u; } v; v.f = f; return v.u;
}
static __device__ inline unsigned packbf(float lo, float hi) {
    unsigned ul = f2u(lo), uh = f2u(hi);
    ul = ul + 0x7FFF + ((ul >> 16) & 1);
    uh = uh + 0x7FFF + ((uh >> 16) & 1);
    return (ul >> 16) | (uh & 0xFFFF0000u);
}

// ---------------- fused prologue: edge-count + feature cvt + weight FOLD/cvt ----------------
// Chebyshev weight folding:  Y = X0(W0-W1+W2)^T + Z1(W1-4W2)^T + Z2'(2W2)^T,
// Z1 = P X0, Z2' = P Z1, P f = dinv * segsum(f[src]*dinv[src]).

static __global__ __launch_bounds__(256) void k_pro(
    const int* __restrict__ dst, int ne, int* __restrict__ counts,
    const float* __restrict__ feat, short* __restrict__ fbf, int n8, int nbE, int nbF,
    const float* __restrict__ w1, const float* __restrict__ w3,
    const float* __restrict__ wm1, const float* __restrict__ wm2,
    short* __restrict__ o1, short* __restrict__ o3,
    short* __restrict__ om1, short* __restrict__ om2) {
    int b = blockIdx.x;
    if (b < nbE) {
        int e = b * 256 + threadIdx.x;
        if (e < ne) atomicAdd(&counts[dst[e]], 1);
        return;
    }
    b -= nbE;
    if (b < nbF) {
        int i = b * 256 + threadIdx.x;
        if (i < n8) {
            f32x4 a = *(const f32x4*)&feat[(size_t)i * 8];
            f32x4 c = *(const f32x4*)&feat[(size_t)i * 8 + 4];
            bf16x8 r;
            r[0] = f2bf(a[0]); r[1] = f2bf(a[1]); r[2] = f2bf(a[2]); r[3] = f2bf(a[3]);
            r[4] = f2bf(c[0]); r[5] = f2bf(c[1]); r[6] = f2bf(c[2]); r[7] = f2bf(c[3]);
            *(bf16x8*)&fbf[(size_t)i * 8] = r;
        }
        return;
    }
    b -= nbF;
    int i = b * 256 + threadIdx.x;   // 0..15359
    if (i < 12288) {
        const float* x = (i < 6144) ? w1 : w3;
        short* y       = (i < 6144) ? o1 : o3;
        int ii = (i < 6144) ? i : i - 6144;
        int r = ii / 48, c = ii % 48;
        int kt = c * 8, seg = kt >> 7, o = kt & 127;
        const float* base = x + (size_t)r * 384;
        float c0, c1, c2;
        if (seg == 0)      { c0 = 1.f;  c1 = -1.f; c2 = 1.f;  }
        else if (seg == 1) { c0 = 0.f;  c1 = 1.f;  c2 = -4.f; }
        else               { c0 = 0.f;  c1 = 0.f;  c2 = 2.f;  }
        bf16x8 rr;
#pragma unroll
        for (int h = 0; h < 2; ++h) {
            f32x4 a0 = *(const f32x4*)&base[o + h * 4];
            f32x4 a1 = *(const f32x4*)&base[128 + o + h * 4];
            f32x4 a2 = *(const f32x4*)&base[256 + o + h * 4];
#pragma unroll
            for (int j = 0; j < 4; ++j)
                rr[h * 4 + j] = f2bf(c0 * a0[j] + c1 * a1[j] + c2 * a2[j]);
        }
        *(bf16x8*)&y[(size_t)r * 384 + kt] = rr;
        return;
    }
    const float* x; short* y; int off;
    if (i < 14336) { x = wm1; y = om1; off = i - 12288; }
    else           { x = wm2; y = om2; off = i - 14336; }
    f32x4 a = *(const f32x4*)&x[(size_t)off * 8];
    f32x4 c = *(const f32x4*)&x[(size_t)off * 8 + 4];
    bf16x8 r;
    r[0] = f2bf(a[0]); r[1] = f2bf(a[1]); r[2] = f2bf(a[2]); r[3] = f2bf(a[3]);
    r[4] = f2bf(c[0]); r[5] = f2bf(c[1]); r[6] = f2bf(c[2]); r[7] = f2bf(c[3]);
    *(bf16x8*)&y[(size_t)off * 8] = r;
}

// ---------------- scans ----------------

static __global__ void k_scan1(const int* __restrict__ counts, int n,
                               int* __restrict__ row_off, int* __restrict__ bsum) {
    __shared__ int s[SCAN_B];
    int t = threadIdx.x;
    int base = blockIdx.x * SCAN_B;
    int v = (base + t < n) ? counts[base + t] : 0;
    s[t] = v;
    __syncthreads();
    for (int off = 1; off < SCAN_B; off <<= 1) {
        int x = 0;
        if (t >= off) x = s[t - off];
        __syncthreads();
        if (t >= off) s[t] += x;
        __syncthreads();
    }
    if (base + t < n) row_off[base + t] = s[t] - v;
    if (t == SCAN_B - 1) bsum[blockIdx.x] = s[t];
}

static __global__ void k_scan2(int* __restrict__ bsum, int nb) {
    __shared__ int s[512];
    int t = threadIdx.x;
    int v = (t < nb) ? bsum[t] : 0;
    s[t] = v;
    __syncthreads();
    for (int off = 1; off < 512; off <<= 1) {
        int x = 0;
        if (t >= off) x = s[t - off];
        __syncthreads();
        if (t >= off) s[t] += x;
        __syncthreads();
    }
    if (t < nb) bsum[t] = s[t] - v;
}

static __global__ void k_scan3(int* __restrict__ row_off, const int* __restrict__ bsum,
                               int n, int ne, int* __restrict__ cursor,
                               const int* __restrict__ counts, float* __restrict__ dinv) {
    int i = blockIdx.x * SCAN_B + threadIdx.x;
    if (i < n) {
        int v = row_off[i] + bsum[blockIdx.x];
        row_off[i] = v;
        cursor[i] = v;
        float d = fmaxf((float)counts[i], 1.0f);
        dinv[i] = rsqrtf(d);
    }
    if (i == 0) row_off[n] = ne;
}

// fill: store (src, dinv[src]) pairs so laps need ONE coalesced 8B load per edge
static __global__ void k_fill(const int* __restrict__ src, const int* __restrict__ dst, int ne,
                              int* __restrict__ cursor, int2* __restrict__ csrw,
                              const float* __restrict__ dinv) {
    int e = blockIdx.x * blockDim.x + threadIdx.x;
    if (e < ne) {
        int d = dst[e];
        int s = src[e];
        int p = atomicAdd(&cursor[d], 1);
        csrw[p] = make_int2(s, (int)f2u(dinv[s]));
    }
}

// ---------------- pure aggregation: out = dinv_i * sum_src Xin[src]*dinv[src] ----------------

static __global__ __launch_bounds__(256) void k_lap(
    const short* __restrict__ Xin,
    const int* __restrict__ row_off, const int2* __restrict__ csrw,
    const float* __restrict__ dinv,
    short* __restrict__ out, int n) {
    int node = blockIdx.x * 4 + (threadIdx.x >> 6);
    if (node >= n) return;
    int l = threadIdx.x & 63;
    const unsigned* Xu = (const unsigned*)Xin;
    int e0 = row_off[node], e1 = row_off[node + 1];
    int deg = e1 - e0;

    int myi = 0; int mydv = 0;
    if (l < deg && l < 64) {
        int2 q = csrw[e0 + l];
        myi = q.x; mydv = q.y;
    }

    float s0 = 0.f, s1 = 0.f;
    int dcap = deg < 64 ? deg : 64;
    for (int base = 0; base < dcap; base += 8) {
        unsigned v[8]; float dv[8];
#pragma unroll
        for (int j = 0; j < 8; ++j) {
            int jj = base + j;
            bool act = (jj < dcap);                       // wave-uniform
            int lane = act ? jj : base;
            int src = __builtin_amdgcn_readlane(myi, lane);
            unsigned dvb = __builtin_amdgcn_readlane(mydv, lane);
            dv[j] = act ? u2f(dvb) : 0.f;
            v[j] = Xu[(size_t)src * 64 + l];
        }
#pragma unroll
        for (int j = 0; j < 8; ++j) {
            s0 += u2f(v[j] << 16) * dv[j];
            s1 += u2f(v[j] & 0xFFFF0000u) * dv[j];
        }
    }
    // rare tail: degree > 64
    for (int base = e0 + 64; base < e1; base += 8) {
        int m = e1 - base;
        int2 qq = make_int2(0, 0);
        if (l < 8 && l < m) qq = csrw[base + l];
        unsigned v[8]; float dv[8];
#pragma unroll
        for (int j = 0; j < 8; ++j) {
            int src = __shfl(qq.x, j, 64);
            int dvb = __shfl(qq.y, j, 64);
            bool act = (j < m);
            if (!act) src = 0;
            dv[j] = act ? u2f((unsigned)dvb) : 0.f;
            v[j] = Xu[(size_t)src * 64 + l];
        }
#pragma unroll
        for (int j = 0; j < 8; ++j) {
            s0 += u2f(v[j] << 16) * dv[j];
            s1 += u2f(v[j] & 0xFFFF0000u) * dv[j];
        }
    }

    float di = dinv[node];
    ((unsigned*)out)[(size_t)node * 64 + l] = packbf(s0 * di, s1 * di);
}

// ---------------- conv1 GEMM (R11 structure) ----------------
// out[M][128] = concat(X0,Z1,Z2')[M][384] @ Wfold^T, epilogue bn(relu(y+b)). bf16 out.

static __global__ __launch_bounds__(512) void k_gemm_conv(
    const short* __restrict__ X0, const short* __restrict__ X1, const short* __restrict__ X2,
    const short* __restrict__ Wbf, const float* __restrict__ bias,
    const float* __restrict__ bng, const float* __restrict__ bnb,
    const float* __restrict__ bnm, const float* __restrict__ bnv,
    int M, short* __restrict__ out) {
    __shared__ short As[2][128 * 32];
    __shared__ short Bs[2][128 * 32];

    const int nwg = gridDim.x;
    const int q = nwg >> 3, r = nwg & 7;
    const int xcd = blockIdx.x & 7, slot = blockIdx.x >> 3;
    const int flat = (xcd < r ? xcd * (q + 1) : r * (q + 1) + (xcd - r) * q) + slot;
    const int m0 = flat * 128;

    const int t = threadIdx.x;
    const int wv = t >> 6;
    const int ln = t & 63;
    const int wr = wv >> 2;
    const int wc = wv & 3;
    const int lr = ln & 15;
    const int lk = ln >> 4;

    const short* segs[3] = {X0, X1, X2};

    f32x4 acc[4][2];
#pragma unroll
    for (int i = 0; i < 4; ++i)
#pragma unroll
        for (int j = 0; j < 2; ++j) acc[i][j] = (f32x4){0.f, 0.f, 0.f, 0.f};

    auto issue = [&](int buf, int kt) {
        const short* Xp = segs[kt >> 7];
        const int klocal = kt & 127;
#pragma unroll
        for (int j = 0; j < 2; ++j) {
            int g = wv * 2 + j;
            int c = g * 64 + ln;
            if (g < 8) {
                int row = c >> 2, sl = c & 3;
                int gm = m0 + row;
                if (gm > M - 1) gm = M - 1;
                const short* src = &Xp[(size_t)gm * 128 + klocal + ((sl ^ ((row >> 1) & 3)) * 8)];
                GL2LDS16(src, &As[buf][g * 512]);
            } else {
                int cb = c - 512;
                int row = cb >> 2, sl = cb & 3;
                const short* src = &Wbf[(size_t)row * 384 + kt + ((sl ^ ((row >> 1) & 3)) * 8)];
                GL2LDS16(src, &Bs[buf][(g - 8) * 512]);
            }
        }
    };
    auto compute = [&](int buf) {
        bf16x8 af[4], bfr[2];
#pragma unroll
        for (int fi = 0; fi < 4; ++fi) {
            int row = wr * 64 + fi * 16 + lr;
            af[fi] = *(const bf16x8*)&As[buf][row * 32 + ((lk ^ ((row >> 1) & 3)) * 8)];
        }
#pragma unroll
        for (int fj = 0; fj < 2; ++fj) {
            int row = wc * 32 + fj * 16 + lr;
            bfr[fj] = *(const bf16x8*)&Bs[buf][row * 32 + ((lk ^ ((row >> 1) & 3)) * 8)];
        }
#pragma unroll
        for (int fi = 0; fi < 4; ++fi)
#pragma unroll
            for (int fj = 0; fj < 2; ++fj)
                acc[fi][fj] = __builtin_amdgcn_mfma_f32_16x16x32_bf16(af[fi], bfr[fj], acc[fi][fj], 0, 0, 0);
    };

    issue(0, 0);
    __syncthreads();
#pragma unroll
    for (int tgt = 0; tgt < 12; ++tgt) {
        if (tgt < 11) issue((tgt + 1) & 1, (tgt + 1) * 32);
        compute(tgt & 1);
        __syncthreads();
    }

#pragma unroll
    for (int fi = 0; fi < 4; ++fi) {
#pragma unroll
        for (int reg = 0; reg < 4; ++reg) {
            int gm = m0 + wr * 64 + fi * 16 + lk * 4 + reg;
            if (gm >= M) continue;
#pragma unroll
            for (int fj = 0; fj < 2; ++fj) {
                int gn = wc * 32 + fj * 16 + lr;
                float y = fmaxf(acc[fi][fj][reg] + bias[gn], 0.f);
                float sc = rsqrtf(bnv[gn] + 1e-5f) * bng[gn];
                y = (y - bnm[gn]) * sc + bnb[gn];
                out[(size_t)gm * 128 + gn] = f2bf(y);
            }
        }
    }
}

// ---------------- conv2 GEMM + fused MLP ----------------
// Phase G: x = relu([h1|Z1|Z2']@W3fold^T + b3) + h1   -> hs[128][136] (LDS, bf16)
// Phase M1: h = relu(x @ Wm1^T + bm1)                 -> hs (overwrite)
// Phase M2: out = h @ Wm2^T + bm2                     -> global fp32
// LDS carve (51.2 KB): GEMM As/Bs = smem[0..16383]; hs = smem[0..17407];
// Wst[2] = smem[17408..25599] (disjoint from As/Bs -> W staging overlaps epilogue).

static __global__ __launch_bounds__(512) void k_gemm_mlp(
    const short* __restrict__ X0, const short* __restrict__ X1, const short* __restrict__ X2,
    const short* __restrict__ Wbf, const float* __restrict__ bias,
    const short* __restrict__ res,
    const short* __restrict__ Wm1bf, const float* __restrict__ bm1,
    const short* __restrict__ Wm2bf, const float* __restrict__ bm2,
    int M, float* __restrict__ out) {
    __shared__ __align__(16) short smem[25600];
    short* As0 = smem;            // [128*32]
    short* As1 = smem + 4096;
    short* Bs0 = smem + 8192;
    short* Bs1 = smem + 12288;
    short* hs  = smem;            // [128][136] after GEMM phase
    short* Wst = smem + 17408;    // 2 x 4096 (MLP1) / 8192 whole-Wm2 (MLP2)

    const int nwg = gridDim.x;
    const int q = nwg >> 3, r = nwg & 7;
    const int xcd = blockIdx.x & 7, slot = blockIdx.x >> 3;
    const int flat = (xcd < r ? xcd * (q + 1) : r * (q + 1) + (xcd - r) * q) + slot;
    const int m0 = flat * 128;

    const int t = threadIdx.x;
    const int wv = t >> 6;
    const int ln = t & 63;
    const int wr = wv >> 2;         // 0..1
    const int wc = wv & 3;          // 0..3
    const int lr = ln & 15;
    const int lk = ln >> 4;

    const short* segs[3] = {X0, X1, X2};

    f32x4 acc[4][2];
#pragma unroll
    for (int i = 0; i < 4; ++i)
#pragma unroll
        for (int j = 0; j < 2; ++j) acc[i][j] = (f32x4){0.f, 0.f, 0.f, 0.f};

    auto issue = [&](int buf, int kt) {
        const short* Xp = segs[kt >> 7];
        const int klocal = kt & 127;
        short* Ab = buf ? As1 : As0;
        short* Bb = buf ? Bs1 : Bs0;
#pragma unroll
        for (int j = 0; j < 2; ++j) {
            int g = wv * 2 + j;
            int c = g * 64 + ln;
            if (g < 8) {
                int row = c >> 2, sl = c & 3;
                int gm = m0 + row;
                if (gm > M - 1) gm = M - 1;
                const short* src = &Xp[(size_t)gm * 128 + klocal + ((sl ^ ((row >> 1) & 3)) * 8)];
                GL2LDS16(src, &Ab[g * 512]);
            } else {
                int cb = c - 512;
                int row = cb >> 2, sl = cb & 3;
                const short* src = &Wbf[(size_t)row * 384 + kt + ((sl ^ ((row >> 1) & 3)) * 8)];
                GL2LDS16(src, &Bb[(g - 8) * 512]);
            }
        }
    };
    auto compute = [&](int buf) {
        short* Ab = buf ? As1 : As0;
        short* Bb = buf ? Bs1 : Bs0;
        bf16x8 af[4], bfr[2];
#pragma unroll
        for (int fi = 0; fi < 4; ++fi) {
            int row = wr * 64 + fi * 16 + lr;
            af[fi] = *(const bf16x8*)&Ab[row * 32 + ((lk ^ ((row >> 1) & 3)) * 8)];
        }
#pragma unroll
        for (int fj = 0; fj < 2; ++fj) {
            int row = wc * 32 + fj * 16 + lr;
            bfr[fj] = *(const bf16x8*)&Bb[row * 32 + ((lk ^ ((row >> 1) & 3)) * 8)];
        }
#pragma unroll
        for (int fi = 0; fi < 4; ++fi)
#pragma unroll
            for (int fj = 0; fj < 2; ++fj)
                acc[fi][fj] = __builtin_amdgcn_mfma_f32_16x16x32_bf16(af[fi], bfr[fj], acc[fi][fj], 0, 0, 0);
    };

    issue(0, 0);
    __syncthreads();
#pragma unroll
    for (int tgt = 0; tgt < 12; ++tgt) {
        if (tgt < 11) issue((tgt + 1) & 1, (tgt + 1) * 32);
        compute(tgt & 1);
        __syncthreads();
    }

    // --- stage Wm1 K-step 0 early (Wst area disjoint from As/Bs & hs) ---
    auto issueW1 = [&](int buf, int kt) {
        int c = t;                                   // 0..511 chunks of 16B
        int row = c >> 2, sl = c & 3;
        const short* src = &Wm1bf[(size_t)row * 128 + kt + ((sl ^ ((row >> 1) & 3)) * 8)];
        GL2LDS16(src, &Wst[buf * 4096 + c * 8]);
    };
    issueW1(0, 0);

    // --- epilogue: x = relu(y+b3) + res  -> hs (bf16, stride 136) ---
#pragma unroll
    for (int fi = 0; fi < 4; ++fi) {
#pragma unroll
        for (int reg = 0; reg < 4; ++reg) {
            int row = wr * 64 + fi * 16 + lk * 4 + reg;
            int gm = m0 + row;
            int gr = gm < M ? gm : M - 1;
#pragma unroll
            for (int fj = 0; fj < 2; ++fj) {
                int gn = wc * 32 + fj * 16 + lr;
                float y = fmaxf(acc[fi][fj][reg] + bias[gn], 0.f) + bf2f(res[(size_t)gr * 128 + gn]);
                hs[row * 136 + gn] = f2bf(y);
            }
        }
    }
    __syncthreads();   // hs visible; Wst[0] landed (vmcnt drained at barrier)

    // --- MLP1: h = relu(x @ Wm1^T + bm1), 4 K-steps, Wst double-buffered ---
    f32x4 acc2[4][2];
#pragma unroll
    for (int i = 0; i < 4; ++i)
#pragma unroll
        for (int j = 0; j < 2; ++j) acc2[i][j] = (f32x4){0.f, 0.f, 0.f, 0.f};

#pragma unroll
    for (int s = 0; s < 4; ++s) {
        if (s < 3) issueW1((s + 1) & 1, (s + 1) * 32);
        int kt = s * 32;
        short* Wb = &Wst[(s & 1) * 4096];
        bf16x8 af[4], bw[2];
#pragma unroll
        for (int fi = 0; fi < 4; ++fi) {
            int row = wr * 64 + fi * 16 + lr;
            af[fi] = *(const bf16x8*)&hs[row * 136 + kt + lk * 8];
        }
#pragma unroll
        for (int fj = 0; fj < 2; ++fj) {
            int row = wc * 32 + fj * 16 + lr;
            bw[fj] = *(const bf16x8*)&Wb[row * 32 + ((lk ^ ((row >> 1) & 3)) * 8)];
        }
#pragma unroll
        for (int fi = 0; fi < 4; ++fi)
#pragma unroll
            for (int fj = 0; fj < 2; ++fj)
                acc2[fi][fj] = __builtin_amdgcn_mfma_f32_16x16x32_bf16(af[fi], bw[fj], acc2[fi][fj], 0, 0, 0);
        __syncthreads();
    }

    // --- stage whole Wm2 [64][128] (row-XOR swizzled), overlap with h-write ---
#pragma unroll
    for (int j = 0; j < 2; ++j) {
        int c = j * 512 + t;               // 0..1023 chunks
        int row = c >> 4, s = c & 15;
        const short* src = &Wm2bf[(size_t)row * 128 + ((s ^ (row & 7)) * 8)];
        GL2LDS16(src, &Wst[c * 8]);
    }
    // h -> hs (overwrite x; all MLP1 hs reads done at last barrier)
#pragma unroll
    for (int fi = 0; fi < 4; ++fi) {
#pragma unroll
        for (int reg = 0; reg < 4; ++reg) {
            int row = wr * 64 + fi * 16 + lk * 4 + reg;
#pragma unroll
            for (int fj = 0; fj < 2; ++fj) {
                int col = wc * 32 + fj * 16 + lr;
                hs[row * 136 + col] = f2bf(fmaxf(acc2[fi][fj][reg] + bm1[col], 0.f));
            }
        }
    }
    __syncthreads();   // h visible; Wm2 landed

    // --- MLP2: out = h @ Wm2^T + bm2 (pure LDS reads, no barriers) ---
    f32x4 acc3[4];
#pragma unroll
    for (int i = 0; i < 4; ++i) acc3[i] = (f32x4){0.f, 0.f, 0.f, 0.f};
#pragma unroll
    for (int s = 0; s < 4; ++s) {
        int kt = s * 32;
        bf16x8 af, bw;
        int brow = wc * 16 + lr;
        int sidx = s * 4 + lk;
        bw = *(const bf16x8*)&Wst[brow * 128 + ((sidx ^ (brow & 7)) * 8)];
#pragma unroll
        for (int fi = 0; fi < 4; ++fi) {
            int row = wr * 64 + fi * 16 + lr;
            af = *(const bf16x8*)&hs[row * 136 + kt + lk * 8];
            acc3[fi] = __builtin_amdgcn_mfma_f32_16x16x32_bf16(af, bw, acc3[fi], 0, 0, 0);
        }
    }

#pragma unroll
    for (int fi = 0; fi < 4; ++fi) {
#pragma unroll
        for (int reg = 0; reg < 4; ++reg) {
            int gm = m0 + wr * 64 + fi * 16 + lk * 4 + reg;
            if (gm >= M) continue;
            int col = wc * 16 + lr;
            out[(size_t)gm * 64 + col] = acc3[fi][reg] + bm2[col];
        }
    }
}

// ---------------- launch ----------------

extern "C" void kernel_launch(void* const* d_in, const int* in_sizes, int n_in,
                              void* d_out, int out_size, void* d_ws, size_t ws_size,
                              hipStream_t stream) {
    const float* features = (const float*)d_in[0];
    const int*   esrc     = (const int*)d_in[1];
    const int*   edst     = (const int*)d_in[2];
    const float* W1   = (const float*)d_in[3];
    const float* b1   = (const float*)d_in[4];
    const float* bng  = (const float*)d_in[5];
    const float* bnb  = (const float*)d_in[6];
    const float* bnm  = (const float*)d_in[7];
    const float* bnv  = (const float*)d_in[8];
    const float* W3   = (const float*)d_in[9];
    const float* b3   = (const float*)d_in[10];
    const float* Wm1  = (const float*)d_in[11];
    const float* bm1  = (const float*)d_in[12];
    const float* Wm2  = (const float*)d_in[13];
    const float* bm2  = (const float*)d_in[14];
    float* out = (float*)d_out;

    const int n  = in_sizes[0] / NF;     // 100000
    const int ne = in_sizes[1];          // 600000

    uint8_t* w = (uint8_t*)d_ws;
    size_t off = 0;
    auto alloc = [&](size_t bytes) -> void* {
        void* p = w + off;
        off = (off + bytes + 255) & ~(size_t)255;
        return p;
    };
    float* dinv   = (float*)alloc((size_t)n * 4);
    int* counts   = (int*)alloc((size_t)n * 4);
    int* row_off  = (int*)alloc(((size_t)n + 1) * 4);
    int* cursor   = (int*)alloc((size_t)n * 4);
    int2* csrw    = (int2*)alloc((size_t)ne * 8);
    int* bsum     = (int*)alloc(4096);
    short* fbf    = (short*)alloc((size_t)n * NF * 2);
    short* bufB   = (short*)alloc((size_t)n * NF * 2);   // Z1
    short* bufC   = (short*)alloc((size_t)n * NF * 2);   // Z2'
    short* bufD   = (short*)alloc((size_t)n * NF * 2);   // h1 (conv1 out, residual)
    short* W1bf   = (short*)alloc((size_t)128 * 384 * 2);  // folded
    short* W3bf   = (short*)alloc((size_t)128 * 384 * 2);  // folded
    short* Wm1bf  = (short*)alloc((size_t)128 * 128 * 2);
    short* Wm2bf  = (short*)alloc((size_t)64 * 128 * 2);
    (void)ws_size;

    const int TB = 256;
    const int nbE = (ne + TB - 1) / TB;
    const int nbN = (n + TB - 1) / TB;
    const int n8  = n * NF / 8;
    const int nbF = (n8 + TB - 1) / TB;

    hipMemsetAsync(counts, 0, (size_t)n * 4, stream);
    k_pro<<<nbE + nbF + 60, TB, 0, stream>>>(edst, ne, counts,
                                             features, fbf, n8, nbE, nbF,
                                             W1, W3, Wm1, Wm2, W1bf, W3bf, Wm1bf, Wm2bf);
    k_scan1<<<nbN, SCAN_B, 0, stream>>>(counts, n, row_off, bsum);
    k_scan2<<<1, 512, 0, stream>>>(bsum, nbN);
    k_scan3<<<nbN, SCAN_B, 0, stream>>>(row_off, bsum, n, ne, cursor, counts, dinv);
    k_fill<<<nbE, TB, 0, stream>>>(esrc, edst, ne, cursor, csrw, dinv);

    const int gm128 = (n + 127) / 128;
    const int nbL   = (n + 3) / 4;   // lap: 4 nodes per 256-thread block

    // ---- conv1 ----
    k_lap<<<nbL, 256, 0, stream>>>(fbf, row_off, csrw, dinv, bufB, n);
    k_lap<<<nbL, 256, 0, stream>>>(bufB, row_off, csrw, dinv, bufC, n);
    k_gemm_conv<<<gm128, 512, 0, stream>>>(fbf, bufB, bufC, W1bf, b1,
                                           bng, bnb, bnm, bnv, n, bufD);

    // ---- conv2 + fused MLP ----
    k_lap<<<nbL, 256, 0, stream>>>(bufD, row_off, csrw, dinv, bufB, n);
    k_lap<<<nbL, 256, 0, stream>>>(bufB, row_off, csrw, dinv, bufC, n);
    k_gemm_mlp<<<gm128, 512, 0, stream>>>(bufD, bufB, bufC, W3bf, b3, bufD,
                                          Wm1bf, bm1, Wm2bf, bm2, n, out);
}

// Round 16
// 261.924 us; speedup vs baseline: 1.3320x; 1.0812x over previous
//
#include <hip/hip_runtime.h>
#include <cstdint>
#include <cstddef>

#define NF 128          // feature width (IN_F == HID_F == 128)
#define OVF_CAP 65536   // overflow edges (deg>64); Poisson(6) data -> ~0 used

typedef __attribute__((ext_vector_type(4))) float f32x4;
typedef __attribute__((ext_vector_type(8))) short bf16x8;

#define GL2LDS16(g, l) __builtin_amdgcn_global_load_lds(                     \
    (const __attribute__((address_space(1))) unsigned*)(g),                  \
    (__attribute__((address_space(3))) unsigned*)(l), 16, 0, 0)

static __device__ inline float bf2f(short u) {
    union { unsigned u; float f; } v;
    v.u = ((unsigned)(unsigned short)u) << 16;
    return v.f;
}
static __device__ inline short f2bf(float f) {
    union { float f; unsigned u; } v; v.f = f;
    unsigned r = v.u + 0x7FFF + ((v.u >> 16) & 1);  // RNE
    return (short)(r >> 16);
}
static __device__ inline float u2f(unsigned u) {
    union { unsigned u; float f; } v; v.u = u; return v.f;
}
static __device__ inline float f2u_f(unsigned u) { return u2f(u); }
static __device__ inline unsigned f2u(float f) {
    union { float f; unsigned u; } v; v.f = f; return v.u;
}
static __device__ inline unsigned packbf(float lo, float hi) {
    unsigned ul = f2u(lo), uh = f2u(hi);
    ul = ul + 0x7FFF + ((ul >> 16) & 1);
    uh = uh + 0x7FFF + ((uh >> 16) & 1);
    return (ul >> 16) | (uh & 0xFFFF0000u);
}

// ---------------- fused prologue: ELL build + feature cvt + weight FOLD/cvt ----------------
// Chebyshev weight folding:  Y = X0(W0-W1+W2)^T + Z1(W1-4W2)^T + Z2'(2W2)^T,
// Z1 = P X0, Z2' = P Z1, P f = dinv * segsum(f[src]*dinv[src]).
// Edge role: r = atomicAdd(cnt[d]); r<64 -> ell[d*64+r]=src, else overflow list.

static __global__ __launch_bounds__(256) void k_pro(
    const int* __restrict__ esrc, const int* __restrict__ edst, int ne,
    int* __restrict__ cnt, int* __restrict__ ell,
    int* __restrict__ ovf_cnt, int2* __restrict__ ovf,
    const float* __restrict__ feat, short* __restrict__ fbf, int n8, int nbE, int nbF,
    const float* __restrict__ w1, const float* __restrict__ w3,
    const float* __restrict__ wm1, const float* __restrict__ wm2,
    short* __restrict__ o1, short* __restrict__ o3,
    short* __restrict__ om1, short* __restrict__ om2) {
    int b = blockIdx.x;
    if (b < nbE) {
        int e = b * 256 + threadIdx.x;
        if (e < ne) {
            int d = edst[e], s = esrc[e];
            int r = atomicAdd(&cnt[d], 1);
            if (r < 64) ell[(size_t)d * 64 + r] = s;
            else {
                int o = atomicAdd(ovf_cnt, 1);
                if (o < OVF_CAP) ovf[o] = make_int2(d, s);
            }
        }
        return;
    }
    b -= nbE;
    if (b < nbF) {
        int i = b * 256 + threadIdx.x;
        if (i < n8) {
            f32x4 a = *(const f32x4*)&feat[(size_t)i * 8];
            f32x4 c = *(const f32x4*)&feat[(size_t)i * 8 + 4];
            bf16x8 r;
            r[0] = f2bf(a[0]); r[1] = f2bf(a[1]); r[2] = f2bf(a[2]); r[3] = f2bf(a[3]);
            r[4] = f2bf(c[0]); r[5] = f2bf(c[1]); r[6] = f2bf(c[2]); r[7] = f2bf(c[3]);
            *(bf16x8*)&fbf[(size_t)i * 8] = r;
        }
        return;
    }
    b -= nbF;
    int i = b * 256 + threadIdx.x;   // 0..15359
    if (i < 12288) {
        const float* x = (i < 6144) ? w1 : w3;
        short* y       = (i < 6144) ? o1 : o3;
        int ii = (i < 6144) ? i : i - 6144;
        int r = ii / 48, c = ii % 48;
        int kt = c * 8, seg = kt >> 7, o = kt & 127;
        const float* base = x + (size_t)r * 384;
        float c0, c1, c2;
        if (seg == 0)      { c0 = 1.f;  c1 = -1.f; c2 = 1.f;  }
        else if (seg == 1) { c0 = 0.f;  c1 = 1.f;  c2 = -4.f; }
        else               { c0 = 0.f;  c1 = 0.f;  c2 = 2.f;  }
        bf16x8 rr;
#pragma unroll
        for (int h = 0; h < 2; ++h) {
            f32x4 a0 = *(const f32x4*)&base[o + h * 4];
            f32x4 a1 = *(const f32x4*)&base[128 + o + h * 4];
            f32x4 a2 = *(const f32x4*)&base[256 + o + h * 4];
#pragma unroll
            for (int j = 0; j < 4; ++j)
                rr[h * 4 + j] = f2bf(c0 * a0[j] + c1 * a1[j] + c2 * a2[j]);
        }
        *(bf16x8*)&y[(size_t)r * 384 + kt] = rr;
        return;
    }
    const float* x; short* y; int off;
    if (i < 14336) { x = wm1; y = om1; off = i - 12288; }
    else           { x = wm2; y = om2; off = i - 14336; }
    f32x4 a = *(const f32x4*)&x[(size_t)off * 8];
    f32x4 c = *(const f32x4*)&x[(size_t)off * 8 + 4];
    bf16x8 r;
    r[0] = f2bf(a[0]); r[1] = f2bf(a[1]); r[2] = f2bf(a[2]); r[3] = f2bf(a[3]);
    r[4] = f2bf(c[0]); r[5] = f2bf(c[1]); r[6] = f2bf(c[2]); r[7] = f2bf(c[3]);
    *(bf16x8*)&y[(size_t)off * 8] = r;
}

// ---------------- pure aggregation: out = dinv_i * sum_src Xin[src]*dinv[src] ----------------
// ELL-64: lane l owns slot l (coalesced 4B); dinv recomputed as rsqrt(max(cnt,1)).
// Overflow edges (deg>64) consumed from the global list (wave-uniform, ~0 iters).

static __global__ __launch_bounds__(256) void k_lap(
    const short* __restrict__ Xin,
    const int* __restrict__ cnt, const int* __restrict__ ell,
    const int* __restrict__ ovf_cnt, const int2* __restrict__ ovf,
    short* __restrict__ out, int n) {
    int node = blockIdx.x * 4 + (threadIdx.x >> 6);
    if (node >= n) return;
    int l = threadIdx.x & 63;
    const unsigned* Xu = (const unsigned*)Xin;
    int deg = cnt[node];
    int dcap = deg < 64 ? deg : 64;

    int myi = 0; float mydv = 0.f;
    if (l < dcap) {
        myi = ell[(size_t)node * 64 + l];
        mydv = rsqrtf(fmaxf((float)cnt[myi], 1.f));
    }

    float s0 = 0.f, s1 = 0.f;
    for (int base = 0; base < dcap; base += 8) {
        unsigned v[8]; float dv[8];
#pragma unroll
        for (int j = 0; j < 8; ++j) {
            int jj = base + j;
            bool act = (jj < dcap);                       // wave-uniform
            int lane = act ? jj : base;
            int src = __builtin_amdgcn_readlane(myi, lane);
            unsigned dvb = __builtin_amdgcn_readlane((int)f2u(mydv), lane);
            dv[j] = act ? u2f(dvb) : 0.f;
            v[j] = Xu[(size_t)src * 64 + l];
        }
#pragma unroll
        for (int j = 0; j < 8; ++j) {
            s0 += u2f(v[j] << 16) * dv[j];
            s1 += u2f(v[j] & 0xFFFF0000u) * dv[j];
        }
    }
    // overflow edges (deg > 64): wave-uniform scan of the tiny global list
    int novf = *ovf_cnt;
    if (novf > 0) {
        if (novf > OVF_CAP) novf = OVF_CAP;
        for (int k = 0; k < novf; ++k) {
            int2 q2 = ovf[k];
            if (q2.x == node) {
                float dw = rsqrtf(fmaxf((float)cnt[q2.y], 1.f));
                unsigned v = Xu[(size_t)q2.y * 64 + l];
                s0 += u2f(v << 16) * dw;
                s1 += u2f(v & 0xFFFF0000u) * dw;
            }
        }
    }

    float di = rsqrtf(fmaxf((float)deg, 1.f));
    ((unsigned*)out)[(size_t)node * 64 + l] = packbf(s0 * di, s1 * di);
}

// ---------------- conv1 GEMM (R11 structure) ----------------
// out[M][128] = concat(X0,Z1,Z2')[M][384] @ Wfold^T, epilogue bn(relu(y+b)). bf16 out.

static __global__ __launch_bounds__(512) void k_gemm_conv(
    const short* __restrict__ X0, const short* __restrict__ X1, const short* __restrict__ X2,
    const short* __restrict__ Wbf, const float* __restrict__ bias,
    const float* __restrict__ bng, const float* __restrict__ bnb,
    const float* __restrict__ bnm, const float* __restrict__ bnv,
    int M, short* __restrict__ out) {
    __shared__ short As[2][128 * 32];
    __shared__ short Bs[2][128 * 32];

    const int nwg = gridDim.x;
    const int q = nwg >> 3, r = nwg & 7;
    const int xcd = blockIdx.x & 7, slot = blockIdx.x >> 3;
    const int flat = (xcd < r ? xcd * (q + 1) : r * (q + 1) + (xcd - r) * q) + slot;
    const int m0 = flat * 128;

    const int t = threadIdx.x;
    const int wv = t >> 6;
    const int ln = t & 63;
    const int wr = wv >> 2;
    const int wc = wv & 3;
    const int lr = ln & 15;
    const int lk = ln >> 4;

    const short* segs[3] = {X0, X1, X2};

    f32x4 acc[4][2];
#pragma unroll
    for (int i = 0; i < 4; ++i)
#pragma unroll
        for (int j = 0; j < 2; ++j) acc[i][j] = (f32x4){0.f, 0.f, 0.f, 0.f};

    auto issue = [&](int buf, int kt) {
        const short* Xp = segs[kt >> 7];
        const int klocal = kt & 127;
#pragma unroll
        for (int j = 0; j < 2; ++j) {
            int g = wv * 2 + j;
            int c = g * 64 + ln;
            if (g < 8) {
                int row = c >> 2, sl = c & 3;
                int gm = m0 + row;
                if (gm > M - 1) gm = M - 1;
                const short* src = &Xp[(size_t)gm * 128 + klocal + ((sl ^ ((row >> 1) & 3)) * 8)];
                GL2LDS16(src, &As[buf][g * 512]);
            } else {
                int cb = c - 512;
                int row = cb >> 2, sl = cb & 3;
                const short* src = &Wbf[(size_t)row * 384 + kt + ((sl ^ ((row >> 1) & 3)) * 8)];
                GL2LDS16(src, &Bs[buf][(g - 8) * 512]);
            }
        }
    };
    auto compute = [&](int buf) {
        bf16x8 af[4], bfr[2];
#pragma unroll
        for (int fi = 0; fi < 4; ++fi) {
            int row = wr * 64 + fi * 16 + lr;
            af[fi] = *(const bf16x8*)&As[buf][row * 32 + ((lk ^ ((row >> 1) & 3)) * 8)];
        }
#pragma unroll
        for (int fj = 0; fj < 2; ++fj) {
            int row = wc * 32 + fj * 16 + lr;
            bfr[fj] = *(const bf16x8*)&Bs[buf][row * 32 + ((lk ^ ((row >> 1) & 3)) * 8)];
        }
#pragma unroll
        for (int fi = 0; fi < 4; ++fi)
#pragma unroll
            for (int fj = 0; fj < 2; ++fj)
                acc[fi][fj] = __builtin_amdgcn_mfma_f32_16x16x32_bf16(af[fi], bfr[fj], acc[fi][fj], 0, 0, 0);
    };

    issue(0, 0);
    __syncthreads();
#pragma unroll
    for (int tgt = 0; tgt < 12; ++tgt) {
        if (tgt < 11) issue((tgt + 1) & 1, (tgt + 1) * 32);
        compute(tgt & 1);
        __syncthreads();
    }

#pragma unroll
    for (int fi = 0; fi < 4; ++fi) {
#pragma unroll
        for (int reg = 0; reg < 4; ++reg) {
            int gm = m0 + wr * 64 + fi * 16 + lk * 4 + reg;
            if (gm >= M) continue;
#pragma unroll
            for (int fj = 0; fj < 2; ++fj) {
                int gn = wc * 32 + fj * 16 + lr;
                float y = fmaxf(acc[fi][fj][reg] + bias[gn], 0.f);
                float sc = rsqrtf(bnv[gn] + 1e-5f) * bng[gn];
                y = (y - bnm[gn]) * sc + bnb[gn];
                out[(size_t)gm * 128 + gn] = f2bf(y);
            }
        }
    }
}

// ---------------- conv2 GEMM + fused MLP ----------------
// Phase G: x = relu([h1|Z1|Z2']@W3fold^T + b3) + h1 -> hs[128][136] (LDS bf16)
// Phase M1: h = relu(x @ Wm1^T + bm1) -> hs      Phase M2: out = h @ Wm2^T + bm2.

static __global__ __launch_bounds__(512) void k_gemm_mlp(
    const short* __restrict__ X0, const short* __restrict__ X1, const short* __restrict__ X2,
    const short* __restrict__ Wbf, const float* __restrict__ bias,
    const short* __restrict__ res,
    const short* __restrict__ Wm1bf, const float* __restrict__ bm1,
    const short* __restrict__ Wm2bf, const float* __restrict__ bm2,
    int M, float* __restrict__ out) {
    __shared__ __align__(16) short smem[25600];
    short* As0 = smem;
    short* As1 = smem + 4096;
    short* Bs0 = smem + 8192;
    short* Bs1 = smem + 12288;
    short* hs  = smem;            // [128][136] after GEMM phase
    short* Wst = smem + 17408;    // 2 x 4096 (MLP1) / 8192 whole-Wm2 (MLP2)

    const int nwg = gridDim.x;
    const int q = nwg >> 3, r = nwg & 7;
    const int xcd = blockIdx.x & 7, slot = blockIdx.x >> 3;
    const int flat = (xcd < r ? xcd * (q + 1) : r * (q + 1) + (xcd - r) * q) + slot;
    const int m0 = flat * 128;

    const int t = threadIdx.x;
    const int wv = t >> 6;
    const int ln = t & 63;
    const int wr = wv >> 2;
    const int wc = wv & 3;
    const int lr = ln & 15;
    const int lk = ln >> 4;

    const short* segs[3] = {X0, X1, X2};

    f32x4 acc[4][2];
#pragma unroll
    for (int i = 0; i < 4; ++i)
#pragma unroll
        for (int j = 0; j < 2; ++j) acc[i][j] = (f32x4){0.f, 0.f, 0.f, 0.f};

    auto issue = [&](int buf, int kt) {
        const short* Xp = segs[kt >> 7];
        const int klocal = kt & 127;
        short* Ab = buf ? As1 : As0;
        short* Bb = buf ? Bs1 : Bs0;
#pragma unroll
        for (int j = 0; j < 2; ++j) {
            int g = wv * 2 + j;
            int c = g * 64 + ln;
            if (g < 8) {
                int row = c >> 2, sl = c & 3;
                int gm = m0 + row;
                if (gm > M - 1) gm = M - 1;
                const short* src = &Xp[(size_t)gm * 128 + klocal + ((sl ^ ((row >> 1) & 3)) * 8)];
                GL2LDS16(src, &Ab[g * 512]);
            } else {
                int cb = c - 512;
                int row = cb >> 2, sl = cb & 3;
                const short* src = &Wbf[(size_t)row * 384 + kt + ((sl ^ ((row >> 1) & 3)) * 8)];
                GL2LDS16(src, &Bb[(g - 8) * 512]);
            }
        }
    };
    auto compute = [&](int buf) {
        short* Ab = buf ? As1 : As0;
        short* Bb = buf ? Bs1 : Bs0;
        bf16x8 af[4], bfr[2];
#pragma unroll
        for (int fi = 0; fi < 4; ++fi) {
            int row = wr * 64 + fi * 16 + lr;
            af[fi] = *(const bf16x8*)&Ab[row * 32 + ((lk ^ ((row >> 1) & 3)) * 8)];
        }
#pragma unroll
        for (int fj = 0; fj < 2; ++fj) {
            int row = wc * 32 + fj * 16 + lr;
            bfr[fj] = *(const bf16x8*)&Bb[row * 32 + ((lk ^ ((row >> 1) & 3)) * 8)];
        }
#pragma unroll
        for (int fi = 0; fi < 4; ++fi)
#pragma unroll
            for (int fj = 0; fj < 2; ++fj)
                acc[fi][fj] = __builtin_amdgcn_mfma_f32_16x16x32_bf16(af[fi], bfr[fj], acc[fi][fj], 0, 0, 0);
    };

    issue(0, 0);
    __syncthreads();
#pragma unroll
    for (int tgt = 0; tgt < 12; ++tgt) {
        if (tgt < 11) issue((tgt + 1) & 1, (tgt + 1) * 32);
        compute(tgt & 1);
        __syncthreads();
    }

    auto issueW1 = [&](int buf, int kt) {
        int c = t;
        int row = c >> 2, sl = c & 3;
        const short* src = &Wm1bf[(size_t)row * 128 + kt + ((sl ^ ((row >> 1) & 3)) * 8)];
        GL2LDS16(src, &Wst[buf * 4096 + c * 8]);
    };
    issueW1(0, 0);

#pragma unroll
    for (int fi = 0; fi < 4; ++fi) {
#pragma unroll
        for (int reg = 0; reg < 4; ++reg) {
            int row = wr * 64 + fi * 16 + lk * 4 + reg;
            int gm = m0 + row;
            int gr = gm < M ? gm : M - 1;
#pragma unroll
            for (int fj = 0; fj < 2; ++fj) {
                int gn = wc * 32 + fj * 16 + lr;
                float y = fmaxf(acc[fi][fj][reg] + bias[gn], 0.f) + bf2f(res[(size_t)gr * 128 + gn]);
                hs[row * 136 + gn] = f2bf(y);
            }
        }
    }
    __syncthreads();

    f32x4 acc2[4][2];
#pragma unroll
    for (int i = 0; i < 4; ++i)
#pragma unroll
        for (int j = 0; j < 2; ++j) acc2[i][j] = (f32x4){0.f, 0.f, 0.f, 0.f};

#pragma unroll
    for (int s = 0; s < 4; ++s) {
        if (s < 3) issueW1((s + 1) & 1, (s + 1) * 32);
        int kt = s * 32;
        short* Wb = &Wst[(s & 1) * 4096];
        bf16x8 af[4], bw[2];
#pragma unroll
        for (int fi = 0; fi < 4; ++fi) {
            int row = wr * 64 + fi * 16 + lr;
            af[fi] = *(const bf16x8*)&hs[row * 136 + kt + lk * 8];
        }
#pragma unroll
        for (int fj = 0; fj < 2; ++fj) {
            int row = wc * 32 + fj * 16 + lr;
            bw[fj] = *(const bf16x8*)&Wb[row * 32 + ((lk ^ ((row >> 1) & 3)) * 8)];
        }
#pragma unroll
        for (int fi = 0; fi < 4; ++fi)
#pragma unroll
            for (int fj = 0; fj < 2; ++fj)
                acc2[fi][fj] = __builtin_amdgcn_mfma_f32_16x16x32_bf16(af[fi], bw[fj], acc2[fi][fj], 0, 0, 0);
        __syncthreads();
    }

#pragma unroll
    for (int j = 0; j < 2; ++j) {
        int c = j * 512 + t;
        int row = c >> 4, s = c & 15;
        const short* src = &Wm2bf[(size_t)row * 128 + ((s ^ (row & 7)) * 8)];
        GL2LDS16(src, &Wst[c * 8]);
    }
#pragma unroll
    for (int fi = 0; fi < 4; ++fi) {
#pragma unroll
        for (int reg = 0; reg < 4; ++reg) {
            int row = wr * 64 + fi * 16 + lk * 4 + reg;
#pragma unroll
            for (int fj = 0; fj < 2; ++fj) {
                int col = wc * 32 + fj * 16 + lr;
                hs[row * 136 + col] = f2bf(fmaxf(acc2[fi][fj][reg] + bm1[col], 0.f));
            }
        }
    }
    __syncthreads();

    f32x4 acc3[4];
#pragma unroll
    for (int i = 0; i < 4; ++i) acc3[i] = (f32x4){0.f, 0.f, 0.f, 0.f};
#pragma unroll
    for (int s = 0; s < 4; ++s) {
        int kt = s * 32;
        bf16x8 af, bw;
        int brow = wc * 16 + lr;
        int sidx = s * 4 + lk;
        bw = *(const bf16x8*)&Wst[brow * 128 + ((sidx ^ (brow & 7)) * 8)];
#pragma unroll
        for (int fi = 0; fi < 4; ++fi) {
            int row = wr * 64 + fi * 16 + lr;
            af = *(const bf16x8*)&hs[row * 136 + kt + lk * 8];
            acc3[fi] = __builtin_amdgcn_mfma_f32_16x16x32_bf16(af, bw, acc3[fi], 0, 0, 0);
        }
    }

#pragma unroll
    for (int fi = 0; fi < 4; ++fi) {
#pragma unroll
        for (int reg = 0; reg < 4; ++reg) {
            int gm = m0 + wr * 64 + fi * 16 + lk * 4 + reg;
            if (gm >= M) continue;
            int col = wc * 16 + lr;
            out[(size_t)gm * 64 + col] = acc3[fi][reg] + bm2[col];
        }
    }
}

// ---------------- launch ----------------

extern "C" void kernel_launch(void* const* d_in, const int* in_sizes, int n_in,
                              void* d_out, int out_size, void* d_ws, size_t ws_size,
                              hipStream_t stream) {
    const float* features = (const float*)d_in[0];
    const int*   esrc     = (const int*)d_in[1];
    const int*   edst     = (const int*)d_in[2];
    const float* W1   = (const float*)d_in[3];
    const float* b1   = (const float*)d_in[4];
    const float* bng  = (const float*)d_in[5];
    const float* bnb  = (const float*)d_in[6];
    const float* bnm  = (const float*)d_in[7];
    const float* bnv  = (const float*)d_in[8];
    const float* W3   = (const float*)d_in[9];
    const float* b3   = (const float*)d_in[10];
    const float* Wm1  = (const float*)d_in[11];
    const float* bm1  = (const float*)d_in[12];
    const float* Wm2  = (const float*)d_in[13];
    const float* bm2  = (const float*)d_in[14];
    float* out = (float*)d_out;

    const int n  = in_sizes[0] / NF;     // 100000
    const int ne = in_sizes[1];          // 600000

    uint8_t* w = (uint8_t*)d_ws;
    size_t off = 0;
    auto alloc = [&](size_t bytes) -> void* {
        void* p = w + off;
        off = (off + bytes + 255) & ~(size_t)255;
        return p;
    };
    int* cnt      = (int*)alloc(((size_t)n + 1) * 4);   // [n] counts + [n] = ovf_cnt
    int* ell      = (int*)alloc((size_t)n * 64 * 4);
    int2* ovf     = (int2*)alloc((size_t)OVF_CAP * 8);
    short* fbf    = (short*)alloc((size_t)n * NF * 2);
    short* bufB   = (short*)alloc((size_t)n * NF * 2);   // Z1
    short* bufC   = (short*)alloc((size_t)n * NF * 2);   // Z2'
    short* bufD   = (short*)alloc((size_t)n * NF * 2);   // h1 (conv1 out, residual)
    short* W1bf   = (short*)alloc((size_t)128 * 384 * 2);  // folded
    short* W3bf   = (short*)alloc((size_t)128 * 384 * 2);  // folded
    short* Wm1bf  = (short*)alloc((size_t)128 * 128 * 2);
    short* Wm2bf  = (short*)alloc((size_t)64 * 128 * 2);
    (void)ws_size;
    int* ovf_cnt = cnt + n;

    const int TB = 256;
    const int nbE = (ne + TB - 1) / TB;
    const int n8  = n * NF / 8;
    const int nbF = (n8 + TB - 1) / TB;

    hipMemsetAsync(cnt, 0, ((size_t)n + 1) * 4, stream);
    k_pro<<<nbE + nbF + 60, TB, 0, stream>>>(esrc, edst, ne, cnt, ell, ovf_cnt, ovf,
                                             features, fbf, n8, nbE, nbF,
                                             W1, W3, Wm1, Wm2, W1bf, W3bf, Wm1bf, Wm2bf);

    const int gm128 = (n + 127) / 128;
    const int nbL   = (n + 3) / 4;   // lap: 4 nodes per 256-thread block

    // ---- conv1:  Z1 = P X0;  Z2' = P Z1;  h1 = bn(relu([X0|Z1|Z2']@W1fold^T+b1)) ----
    k_lap<<<nbL, 256, 0, stream>>>(fbf, cnt, ell, ovf_cnt, ovf, bufB, n);
    k_lap<<<nbL, 256, 0, stream>>>(bufB, cnt, ell, ovf_cnt, ovf, bufC, n);
    k_gemm_conv<<<gm128, 512, 0, stream>>>(fbf, bufB, bufC, W1bf, b1,
                                           bng, bnb, bnm, bnv, n, bufD);

    // ---- conv2 + fused MLP ----
    k_lap<<<nbL, 256, 0, stream>>>(bufD, cnt, ell, ovf_cnt, ovf, bufB, n);
    k_lap<<<nbL, 256, 0, stream>>>(bufB, cnt, ell, ovf_cnt, ovf, bufC, n);
    k_gemm_mlp<<<gm128, 512, 0, stream>>>(bufD, bufB, bufC, W3bf, b3, bufD,
                                          Wm1bf, bm1, Wm2bf, bm2, n, out);
}